// Round 8
// baseline (162.269 us; speedup 1.0000x reference)
//
#include <hip/hip_runtime.h>
#include <hip/hip_bf16.h>
#include <math.h>

#define HDIM 150

typedef __bf16 bf16x8 __attribute__((ext_vector_type(8)));
typedef __bf16 bf16x4 __attribute__((ext_vector_type(4)));
typedef float  f32x4  __attribute__((ext_vector_type(4)));

// ---------------------------------------------------------------------------
// fully unrolled Batcher odd-even mergesort, n = 16
// ---------------------------------------------------------------------------
__device__ __forceinline__ void cswap(float& a, float& b) {
    float lo = fminf(a, b);
    float hi = fmaxf(a, b);
    a = lo; b = hi;
}

__device__ __forceinline__ void sort16(float v[16]) {
#pragma unroll
    for (int pp = 1; pp < 16; pp <<= 1) {
#pragma unroll
        for (int k = pp; k >= 1; k >>= 1) {
#pragma unroll
            for (int j = k & (pp - 1); j + k < 16; j += 2 * k) {
#pragma unroll
                for (int i = 0; i < k; ++i) {
                    if ((i + j) / (2 * pp) == (i + j + k) / (2 * pp))
                        cswap(v[i + j], v[i + j + k]);
                }
            }
        }
    }
}

// ---------------------------------------------------------------------------
// k_all R16: R14 structure with 512-thread blocks (8 waves).
// Rationale: grid 1024 x 4 waves could never exceed 50% occupancy (4096 of
// 8192 wave slots). Same 32 sites/block, same per-block totals; each wave now
// runs 8 MLP tiles instead of 16 -> 8192 waves total, 4 blocks x 512 thr =
// 2048 thr/CU = full thread capacity, occupancy ceiling 100%.
//  * x gather issued AFTER bar2 (R15 lesson: vmcnt is in-order; gathers
//    issued before staging serialize the prologue behind scatter latency).
//  * prologue split 8 ways (blob build: 60 dwords/lane over 8 chunks).
//  * agg: 16 threads/site, sort16 + shfl_xor(8) bitonic-halver merge
//    (lower-median-of-32 identity, verified in R11).
//  * head MFMA on waves 0..3 (short phase; waves 4..7 wait at the barrier).
//
// LDS overlay (39424 B -> 4 blocks/CU):
//   R0 [0,24000): phase A = W1|b1@2700|W2@2850 staging (16.2KB)
//                 phase B = sH (32*264 bf16 = 16896 B)
//                 phase D = W3 staging (6000 f32 = 24000 B)
//   R1 [24064,39424): phase A = fragment blob (15 tiles x 1KB)
//                 phase C/D = sAgg@24064 | sB3@29696 | sW4@30336 | sPart@30976
// ---------------------------------------------------------------------------
#define FB_OFF     24064                 // frag blob (phase A)
#define AGG_OFF    24064                 // float[32*44] = 5632 (phase C)
#define B3_OFF     29696                 // float[160]
#define W4_OFF     30336                 // float[160]
#define PART_OFF   30976                 // float[32]
#define SMEM_TOTAL 39424

__global__ __launch_bounds__(512, 8) void k_all(
    const float* __restrict__ x, const int* __restrict__ kmer,
    const int* __restrict__ indices, const float* __restrict__ emb,
    const float* __restrict__ W1, const float* __restrict__ b1,
    const float* __restrict__ W2, const float* __restrict__ b2,
    const float* __restrict__ W3, const float* __restrict__ b3,
    const float* __restrict__ W4, const float* __restrict__ b4,
    float* __restrict__ out, int Gtot)
{
    __shared__ __align__(16) char smem[SMEM_TOTAL];

    const int tid  = threadIdx.x;
    const int lane = tid & 63;
    const int wv   = tid >> 6;           // 0..7
    const int m    = lane & 15;
    const int q    = lane >> 4;

    const int gblk  = blockIdx.x * 32;           // first site of this block
    const int rbase = gblk * 32;                 // first flat read-slot

    // ---- read indices + emb chain (2 groups of 64 reads per wave) ----
    int          rg[2];
    unsigned int egp[2];                         // packed bf16 (ex,ey)
    {
        const int lim = Gtot * 32 - 1;
#pragma unroll
        for (int g = 0; g < 2; ++g) {
            int fl = rbase + wv * 128 + g * 64 + lane;
            rg[g] = indices[fl > lim ? lim : fl];
        }
        int kk[2];
#pragma unroll
        for (int g = 0; g < 2; ++g) kk[g] = kmer[rg[g]];
        const float2* emb2 = (const float2*)emb;
#pragma unroll
        for (int g = 0; g < 2; ++g) {
            float2 e = emb2[kk[g]];
            __bf16 bx = (__bf16)e.x, by = (__bf16)e.y;
            unsigned short ux, uy;
            __builtin_memcpy(&ux, &bx, 2);
            __builtin_memcpy(&uy, &by, 2);
            egp[g] = (unsigned int)ux | ((unsigned int)uy << 16);
        }
    }

    // ---- phase A: stage W1|b1|W2, build fragment blob in LDS ----
    float* sWgt = (float*)smem;                  // [0,16200) floats
    for (int e = tid; e < 2700; e += 512) sWgt[e] = W1[e];
    for (int e = tid; e < 150;  e += 512) sWgt[2700 + e] = b1[e];
    for (int e = tid; e < 1200; e += 512) sWgt[2850 + e] = W2[e];
    __syncthreads();                             // bar1

    unsigned int* fb = (unsigned int*)(smem + FB_OFF);
    {
        // 60 dwords per lane split over 8 thread-chunks: 8,8,8,8,7,7,7,7
        const int c  = tid >> 6;
        const int d0 = (c < 4) ? c * 8 : 32 + (c - 4) * 7;
        const int dn = (c < 4) ? 8 : 7;
        for (int dd = 0; dd < dn; ++dd) {
            const int d = d0 + dd;
            float v0 = 0.f, v1 = 0.f;
            if (d < 40) {
                int n = d >> 2, j0 = (d & 3) * 2;
                // permuted hidden rows for the register relay:
                //   tile 2kt   row(4q+r) = hidden 32kt+8q+r
                //   tile 2kt+1 row(4q+r) = hidden 32kt+8q+4+r
                int hid = 32 * (n >> 1) + 8 * (m >> 2) + 4 * (n & 1) + (m & 3);
                if (hid < HDIM) {
                    int k0 = q * 8 + j0, k1 = k0 + 1;
                    v0 = (k0 < 18) ? sWgt[k0 * HDIM + hid] : (k0 == 18 ? sWgt[2700 + hid] : 0.f);
                    v1 = (k1 < 18) ? sWgt[k1 * HDIM + hid] : (k1 == 18 ? sWgt[2700 + hid] : 0.f);
                }
            } else {
                int kt = (d - 40) >> 2, j0 = ((d - 40) & 3) * 2;
                int k0 = kt * 32 + q * 8 + j0, k1 = k0 + 1;
                if (m < 8) {
                    v0 = (k0 < HDIM) ? sWgt[2850 + k0 * 8 + m]
                                     : (k0 == HDIM ? b2[m] : 0.f);   // b2 row
                    v1 = (k1 < HDIM) ? sWgt[2850 + k1 * 8 + m]
                                     : (k1 == HDIM ? b2[m] : 0.f);
                }
            }
            __bf16 h0 = (__bf16)v0, h1 = (__bf16)v1;
            unsigned short u0, u1;
            __builtin_memcpy(&u0, &h0, 2);
            __builtin_memcpy(&u1, &h1, 2);
            fb[(d >> 2) * 256 + lane * 4 + (d & 3)] =
                (unsigned int)u0 | ((unsigned int)u1 << 16);
        }
    }
    __syncthreads();                             // bar2

    // ---- lanes pull their 15 fragment uint4s into registers ----
    uint4 B16[15];
    const uint4* fb4 = (const uint4*)fb;
#pragma unroll
    for (int i = 0; i < 15; ++i) B16[i] = fb4[i * 64 + lane];
    const bf16x8* fr = (const bf16x8*)B16;       // fr[0..9]=fA1, fr[10..14]=fA2

    const char* xg = (const char*)x;

    // ---- 2-tile-deep register pipeline for the x gather ----
    f32x4 xa[2][2];
    auto issueTile = [&](int t) {
        int rr = __shfl(rg[t >> 2], ((t & 3) << 4) + m);
        if (q < 2) {
            const f32x4* src = (const f32x4*)(xg + (size_t)rr * 64 + (size_t)q * 32);
            xa[t & 1][0] = src[0];
            xa[t & 1][1] = src[1];
        }
    };
    issueTile(0);
    issueTile(1);

    __bf16* sH = (__bf16*)smem;                  // R0 reused: weights dead
    const f32x4 zero = {0.f, 0.f, 0.f, 0.f};

#pragma unroll
    for (int t = 0; t < 8; ++t) {
        unsigned int ew = __shfl((int)egp[t >> 2], ((t & 3) << 4) + m);

        // input B-fragment: B[k = q*8+j][n = read m]
        bf16x8 bin;
        if (q < 2) {
            f32x4 u0 = xa[t & 1][0];
            f32x4 u1 = xa[t & 1][1];
            bin[0] = (__bf16)u0[0]; bin[1] = (__bf16)u0[1];
            bin[2] = (__bf16)u0[2]; bin[3] = (__bf16)u0[3];
            bin[4] = (__bf16)u1[0]; bin[5] = (__bf16)u1[1];
            bin[6] = (__bf16)u1[2]; bin[7] = (__bf16)u1[3];
        } else if (q == 2) {
            unsigned short lo = (unsigned short)(ew & 0xffffu);
            unsigned short hi = (unsigned short)(ew >> 16);
            __bf16 bx, by;
            __builtin_memcpy(&bx, &lo, 2);
            __builtin_memcpy(&by, &hi, 2);
            bin[0] = bx; bin[1] = by;
            bin[2] = (__bf16)1.0f;   // bias-1 input at k==18
            bin[3] = (__bf16)0.f; bin[4] = (__bf16)0.f;
            bin[5] = (__bf16)0.f; bin[6] = (__bf16)0.f; bin[7] = (__bf16)0.f;
        } else {
#pragma unroll
            for (int j = 0; j < 8; ++j) bin[j] = (__bf16)0.f;
        }

        // refill this ring slot with tile t+2 (loads overlap the MFMAs)
        if (t < 6) issueTile(t + 2);

        // layer1 tile-pair -> relu/pack -> layer2, all in registers.
        f32x4 c2a = zero, c2b = zero;
#pragma unroll
        for (int kt = 0; kt < 5; ++kt) {
            f32x4 ca = __builtin_amdgcn_mfma_f32_16x16x32_bf16(fr[2 * kt],     bin, zero, 0, 0, 0);
            f32x4 cb = __builtin_amdgcn_mfma_f32_16x16x32_bf16(fr[2 * kt + 1], bin, zero, 0, 0, 0);
            bf16x8 bh;
            bh[0] = (__bf16)fmaxf(ca[0], 0.f); bh[1] = (__bf16)fmaxf(ca[1], 0.f);
            bh[2] = (__bf16)fmaxf(ca[2], 0.f); bh[3] = (__bf16)fmaxf(ca[3], 0.f);
            bh[4] = (__bf16)fmaxf(cb[0], 0.f); bh[5] = (__bf16)fmaxf(cb[1], 0.f);
            bh[6] = (__bf16)fmaxf(cb[2], 0.f); bh[7] = (__bf16)fmaxf(cb[3], 0.f);
            if (kt == 4 && q == 2) bh[6] = (__bf16)1.0f;   // bias row k==150
            if (kt & 1) c2b = __builtin_amdgcn_mfma_f32_16x16x32_bf16(fr[10 + kt], bh, c2b, 0, 0, 0);
            else        c2a = __builtin_amdgcn_mfma_f32_16x16x32_bf16(fr[10 + kt], bh, c2a, 0, 0, 0);
        }

        // h -> LDS (never touches HBM); b2 folded via bias row
        if (q < 2) {
            int br   = wv * 128 + t * 16 + m;    // block read idx
            int site = br >> 5, mm = br & 31;
            bf16x4 o;
            o[0] = (__bf16)fmaxf(c2a[0] + c2b[0], 0.f);
            o[1] = (__bf16)fmaxf(c2a[1] + c2b[1], 0.f);
            o[2] = (__bf16)fmaxf(c2a[2] + c2b[2], 0.f);
            o[3] = (__bf16)fmaxf(c2a[3] + c2b[3], 0.f);
            *(bf16x4*)(sH + site * 264 + mm * 8 + q * 4) = o;
        }
    }
    __syncthreads();   // bar3: MLP done; fb reads done -> sAgg region reusable

    float* sAgg = (float*)(smem + AGG_OFF);
    float* sPart= (float*)(smem + PART_OFF);

    // ---- aggregation: 16 threads/site (2 halves x 8 ch) ----
    const int sg = tid >> 4, p = tid & 7;
    {
        const int hf_ = (tid >> 3) & 1;          // half: reads 0..15 / 16..31
        float v[16];
        float sum = 0.f, sumsq = 0.f;
#pragma unroll
        for (int i = 0; i < 16; ++i) {
            float vv = (float)sH[sg * 264 + (hf_ * 16 + i) * 8 + p];
            v[i] = vv;
            sum += vv;
            sumsq = fmaf(vv, vv, sumsq);
        }
        sort16(v);

        // lower median of 32 = max_i min(a[i], b[15-i])  (bitonic halver)
        float med = -1e30f, mn = v[0], mx = v[15];
#pragma unroll
        for (int i = 0; i < 16; ++i) {
            float tp = __shfl_xor(v[15 - i], 8);   // partner's v[15-i]
            if (i == 0)  mx = fmaxf(v[15], tp);    // tp = partner max
            if (i == 15) mn = fminf(v[0], tp);     // tp = partner min
            med = fmaxf(med, fminf(v[i], tp));
        }
        float s1  = sum   + __shfl_xor(sum, 8);
        float ss1 = sumsq + __shfl_xor(sumsq, 8);
        float mean = s1 * (1.f / 32.f);
        float var  = fmaxf((ss1 - 32.f * mean * mean) * (1.f / 31.f), 0.f);

        if (!(tid & 8)) {
            sAgg[sg * 44 + 0 * 8 + p] = mean;
            sAgg[sg * 44 + 1 * 8 + p] = var;
            sAgg[sg * 44 + 2 * 8 + p] = mn;
            sAgg[sg * 44 + 3 * 8 + p] = med;
            sAgg[sg * 44 + 4 * 8 + p] = mx;
        }
    }
    __syncthreads();   // bar4: all sH reads done -> R0 reusable for W3

    // ---- phase D: stage W3 (+b3/W4) ----
    float* sW3  = (float*)smem;                  // [0,24000) floats
    float* sB3  = (float*)(smem + B3_OFF);
    float* sW4  = (float*)(smem + W4_OFF);
    for (int e = tid; e < 6000; e += 512) sW3[e] = W3[e];
    if (tid < 160) {
        sB3[tid] = (tid < HDIM) ? b3[tid] : 0.f;
        sW4[tid] = (tid < HDIM) ? W4[tid] : 0.f;
    }
    __syncthreads();   // bar5

    // ---- head MLP via MFMA on waves 0..3: Z[j][site] = W3^T @ AGG ----
    float sacc = 0.f;
    if (wv < 4) {
        const int jthalf = wv >> 1, sh = wv & 1;

        // head A-fragment: tile (jt,kc): A[row=jt*16+m][k=kc*32+q*8+j]
        uint4 HF[10];
#pragma unroll
        for (int i = 0; i < 10; ++i) {
            int jt = jthalf * 5 + (i >> 1), kc = i & 1;
            int row = jt * 16 + m;
            unsigned int w[4];
#pragma unroll
            for (int dw = 0; dw < 4; ++dw) {
                int k0 = kc * 32 + q * 8 + dw * 2, k1 = k0 + 1;
                float v0 = (k0 < 40 && row < HDIM) ? sW3[k0 * HDIM + row] : 0.f;
                float v1 = (k1 < 40 && row < HDIM) ? sW3[k1 * HDIM + row] : 0.f;
                __bf16 h0 = (__bf16)v0, h1 = (__bf16)v1;
                unsigned short u0, u1;
                __builtin_memcpy(&u0, &h0, 2);
                __builtin_memcpy(&u1, &h1, 2);
                w[dw] = (unsigned int)u0 | ((unsigned int)u1 << 16);
            }
            HF[i] = make_uint4(w[0], w[1], w[2], w[3]);
        }
        const bf16x8* hf = (const bf16x8*)HF;

        // B-frag: lane(m,q) holds AGG[k=kc*32+q*8+j][site sh*16+m], hi/lo split
        const int site = sh * 16 + m;
        const float* ar = sAgg + site * 44;
        bf16x8 bh0, bl0, bh1, bl1;
        {
            float4 a0 = *(const float4*)(ar + q * 8);
            float4 a1 = *(const float4*)(ar + q * 8 + 4);
            float va[8] = {a0.x, a0.y, a0.z, a0.w, a1.x, a1.y, a1.z, a1.w};
#pragma unroll
            for (int j = 0; j < 8; ++j) {
                __bf16 hi = (__bf16)va[j];
                bh0[j] = hi;
                bl0[j] = (__bf16)(va[j] - (float)hi);
            }
        }
        if (q == 0) {   // kc=1 covers k = 32..39 (stat 4); other q are zero
            float4 a0 = *(const float4*)(ar + 32);
            float4 a1 = *(const float4*)(ar + 36);
            float va[8] = {a0.x, a0.y, a0.z, a0.w, a1.x, a1.y, a1.z, a1.w};
#pragma unroll
            for (int j = 0; j < 8; ++j) {
                __bf16 hi = (__bf16)va[j];
                bh1[j] = hi;
                bl1[j] = (__bf16)(va[j] - (float)hi);
            }
        } else {
#pragma unroll
            for (int j = 0; j < 8; ++j) { bh1[j] = (__bf16)0.f; bl1[j] = (__bf16)0.f; }
        }

        const float4* b3v = (const float4*)sB3;
        const float4* w4v = (const float4*)sW4;
#pragma unroll
        for (int jj = 0; jj < 5; ++jj) {
            int jt = jthalf * 5 + jj;
            float4 bi = b3v[jt * 4 + q];         // rows jt*16+q*4 .. +3
            f32x4 acc = {bi.x, bi.y, bi.z, bi.w};
            acc = __builtin_amdgcn_mfma_f32_16x16x32_bf16(hf[jj * 2 + 0], bh0, acc, 0, 0, 0);
            acc = __builtin_amdgcn_mfma_f32_16x16x32_bf16(hf[jj * 2 + 0], bl0, acc, 0, 0, 0);
            acc = __builtin_amdgcn_mfma_f32_16x16x32_bf16(hf[jj * 2 + 1], bh1, acc, 0, 0, 0);
            acc = __builtin_amdgcn_mfma_f32_16x16x32_bf16(hf[jj * 2 + 1], bl1, acc, 0, 0, 0);
            float4 w4q = w4v[jt * 4 + q];
            sacc = fmaf(fmaxf(acc[0], 0.f), w4q.x, sacc);
            sacc = fmaf(fmaxf(acc[1], 0.f), w4q.y, sacc);
            sacc = fmaf(fmaxf(acc[2], 0.f), w4q.z, sacc);
            sacc = fmaf(fmaxf(acc[3], 0.f), w4q.w, sacc);
        }
        // reduce over the 4 q row-groups (j within tile)
        sacc += __shfl_xor(sacc, 16);
        sacc += __shfl_xor(sacc, 32);
        if (jthalf == 1 && lane < 16) sPart[sh * 16 + lane] = sacc;
    }
    __syncthreads();   // bar6
    if (wv < 2 && lane < 16) {
        int s2 = (wv & 1) * 16 + lane;
        float zf = sacc + sPart[s2] + b4[0];
        if (gblk + s2 < Gtot) out[gblk + s2] = 1.f / (1.f + expf(-zf));
    }
}

// ---------------------------------------------------------------------------
extern "C" void kernel_launch(void* const* d_in, const int* in_sizes, int n_in,
                              void* d_out, int out_size, void* d_ws, size_t ws_size,
                              hipStream_t stream) {
    const float* x       = (const float*)d_in[0];
    const int*   kmer    = (const int*)  d_in[1];
    const int*   indices = (const int*)  d_in[2];
    const float* emb     = (const float*)d_in[3];
    const float* W1      = (const float*)d_in[4];
    const float* b1      = (const float*)d_in[5];
    const float* W2      = (const float*)d_in[6];
    const float* b2      = (const float*)d_in[7];
    const float* W3      = (const float*)d_in[8];
    const float* b3      = (const float*)d_in[9];
    const float* W4      = (const float*)d_in[10];
    const float* b4      = (const float*)d_in[11];

    float* out = (float*)d_out;
    const int G = out_size;

    const int grid = (G + 31) / 32;              // 32 sites / block
    k_all<<<grid, 512, 0, stream>>>(x, kmer, indices, emb,
                                    W1, b1, W2, b2, W3, b3, W4, b4,
                                    out, G);
}

// Round 9
// 46.214 us; speedup vs baseline: 3.5112x; 3.5112x over previous
//
#include <hip/hip_runtime.h>
#include <hip/hip_bf16.h>
#include <math.h>

#define HDIM 150

typedef __bf16 bf16x8 __attribute__((ext_vector_type(8)));
typedef __bf16 bf16x4 __attribute__((ext_vector_type(4)));
typedef float  f32x4  __attribute__((ext_vector_type(4)));

// ---------------------------------------------------------------------------
// fully unrolled Batcher odd-even mergesort, n = 16
// ---------------------------------------------------------------------------
__device__ __forceinline__ void cswap(float& a, float& b) {
    float lo = fminf(a, b);
    float hi = fmaxf(a, b);
    a = lo; b = hi;
}

__device__ __forceinline__ void sort16(float v[16]) {
#pragma unroll
    for (int pp = 1; pp < 16; pp <<= 1) {
#pragma unroll
        for (int k = pp; k >= 1; k >>= 1) {
#pragma unroll
            for (int j = k & (pp - 1); j + k < 16; j += 2 * k) {
#pragma unroll
                for (int i = 0; i < k; ++i) {
                    if ((i + j) / (2 * pp) == (i + j + k) / (2 * pp))
                        cswap(v[i + j], v[i + j + k]);
                }
            }
        }
    }
}

// ---------------------------------------------------------------------------
// k_all R17: R14 structure + register diet for a 5th wave/SIMD.
// R16 post-mortem: occupancy is REGISTER-bound (83% occ at forced 32 regs w/
// massive spill). R14's ~124 unified regs (64 VGPR + 60 AGPR fragments) pin
// 4 waves/SIMD. Diet: layer-1 A-fragments (40 regs) stay in LDS where the
// prologue built them; read fa/fb per kt via ds_read_b128 (lane*16 ->
// contiguous 1KB/wave, 2-way bank alias = free). Layer-2 frags (20 regs)
// stay register-resident. Unified ~85-95 -> __launch_bounds__(256,5).
// LDS kept <= 32768/5-blocks: W3 staged as bf16 (12 KB) in phase D.
//
// LDS overlay (32256 B -> 5 blocks/CU):
//   [0,16200)      phase A: W1|b1@2700|W2@2850 staging (f32)
//   [0,16896)      phase B: sH (32*264 bf16)       [after bar2]
//   [0,12000)      phase D: W3 staging (bf16)      [after bar4]
//   [16896,32256)  phase A/B: frag blob, 15 tiles x 1KB
//                  tiles 0..9 (L1, read from LDS through the MLP)
//                  tiles 10..14 (L2, pulled to regs right after bar2)
//   [16896,22528)  phase C: sAgg (32*44 f32)       [after bar3; L1 tiles dead]
//   [22528,23168)  sB3 | [23168,23808) sW4 | [23808,23936) sPart
// Barriers: bar1 (W staged) -> bar2 (blob built; sWgt dead) -> MLP ->
// bar3 (sH done; L1 tiles dead) -> agg -> bar4 (sH dead) -> stage W3 ->
// bar5 -> head MFMA -> bar6 -> out.
// ---------------------------------------------------------------------------
#define FB_OFF     16896                 // frag blob base
#define AGG_OFF    16896                 // sAgg overlays L1 tiles after bar3
#define B3_OFF     22528
#define W4_OFF     23168
#define PART_OFF   23808
#define SMEM_TOTAL 32256

__global__ __launch_bounds__(256, 5) void k_all(
    const float* __restrict__ x, const int* __restrict__ kmer,
    const int* __restrict__ indices, const float* __restrict__ emb,
    const float* __restrict__ W1, const float* __restrict__ b1,
    const float* __restrict__ W2, const float* __restrict__ b2,
    const float* __restrict__ W3, const float* __restrict__ b3,
    const float* __restrict__ W4, const float* __restrict__ b4,
    float* __restrict__ out, int Gtot)
{
    __shared__ __align__(16) char smem[SMEM_TOTAL];

    const int tid  = threadIdx.x;
    const int lane = tid & 63;
    const int wv   = tid >> 6;
    const int m    = lane & 15;
    const int q    = lane >> 4;

    const int gblk  = blockIdx.x * 32;           // first site of this block
    const int rbase = gblk * 32;                 // first flat read-slot

    // ---- read indices + emb chain (4 groups of 64 reads per wave) ----
    int          rg[4];
    unsigned int egp[4];                         // packed bf16 (ex,ey)
    {
        const int lim = Gtot * 32 - 1;
#pragma unroll
        for (int g = 0; g < 4; ++g) {
            int fl = rbase + wv * 256 + g * 64 + lane;
            rg[g] = indices[fl > lim ? lim : fl];
        }
        int kk[4];
#pragma unroll
        for (int g = 0; g < 4; ++g) kk[g] = kmer[rg[g]];
        const float2* emb2 = (const float2*)emb;
#pragma unroll
        for (int g = 0; g < 4; ++g) {
            float2 e = emb2[kk[g]];
            __bf16 bx = (__bf16)e.x, by = (__bf16)e.y;
            unsigned short ux, uy;
            __builtin_memcpy(&ux, &bx, 2);
            __builtin_memcpy(&uy, &by, 2);
            egp[g] = (unsigned int)ux | ((unsigned int)uy << 16);
        }
    }

    // ---- phase A: stage W1|b1|W2, build fragment blob in LDS ----
    float* sWgt = (float*)smem;                  // [0,16200) bytes as f32
    for (int e = tid; e < 2700; e += 256) sWgt[e] = W1[e];
    for (int e = tid; e < 150;  e += 256) sWgt[2700 + e] = b1[e];
    for (int e = tid; e < 1200; e += 256) sWgt[2850 + e] = W2[e];
    __syncthreads();                             // bar1

    unsigned int* fb = (unsigned int*)(smem + FB_OFF);
    {
        const int c = tid >> 6;                  // dword chunk 0..3
        for (int d = c * 15; d < c * 15 + 15; ++d) {
            float v0 = 0.f, v1 = 0.f;
            if (d < 40) {
                int n = d >> 2, j0 = (d & 3) * 2;
                // permuted hidden rows for the register relay:
                //   tile 2kt   row(4q+r) = hidden 32kt+8q+r
                //   tile 2kt+1 row(4q+r) = hidden 32kt+8q+4+r
                int hid = 32 * (n >> 1) + 8 * (m >> 2) + 4 * (n & 1) + (m & 3);
                if (hid < HDIM) {
                    int k0 = q * 8 + j0, k1 = k0 + 1;
                    v0 = (k0 < 18) ? sWgt[k0 * HDIM + hid] : (k0 == 18 ? sWgt[2700 + hid] : 0.f);
                    v1 = (k1 < 18) ? sWgt[k1 * HDIM + hid] : (k1 == 18 ? sWgt[2700 + hid] : 0.f);
                }
            } else {
                int kt = (d - 40) >> 2, j0 = ((d - 40) & 3) * 2;
                int k0 = kt * 32 + q * 8 + j0, k1 = k0 + 1;
                if (m < 8) {
                    v0 = (k0 < HDIM) ? sWgt[2850 + k0 * 8 + m]
                                     : (k0 == HDIM ? b2[m] : 0.f);   // b2 row
                    v1 = (k1 < HDIM) ? sWgt[2850 + k1 * 8 + m]
                                     : (k1 == HDIM ? b2[m] : 0.f);
                }
            }
            __bf16 h0 = (__bf16)v0, h1 = (__bf16)v1;
            unsigned short u0, u1;
            __builtin_memcpy(&u0, &h0, 2);
            __builtin_memcpy(&u1, &h1, 2);
            fb[(d >> 2) * 256 + lane * 4 + (d & 3)] =
                (unsigned int)u0 | ((unsigned int)u1 << 16);
        }
    }
    __syncthreads();                             // bar2 (sWgt dead)

    // ---- layer2 fragments (tiles 10..14) pulled into registers ----
    uint4 B2F[5];
    const uint4* fb4 = (const uint4*)fb;
#pragma unroll
    for (int i = 0; i < 5; ++i) B2F[i] = fb4[(10 + i) * 64 + lane];
    const bf16x8* fr2 = (const bf16x8*)B2F;      // fr2[0..4] = layer2 frags

    const char* fL1 = (const char*)fb;           // L1 tiles, read per kt
    const int   lofs = lane * 16;

    const char* xg = (const char*)x;

    // ---- 2-tile-deep register pipeline for the x gather ----
    f32x4 xa[2][2];
    auto issueTile = [&](int t) {
        int rr = __shfl(rg[t >> 2], ((t & 3) << 4) + m);
        if (q < 2) {
            const f32x4* src = (const f32x4*)(xg + (size_t)rr * 64 + (size_t)q * 32);
            xa[t & 1][0] = src[0];
            xa[t & 1][1] = src[1];
        }
    };
    issueTile(0);
    issueTile(1);

    __bf16* sH = (__bf16*)smem;                  // overlays dead sWgt
    const f32x4 zero = {0.f, 0.f, 0.f, 0.f};

#pragma unroll
    for (int t = 0; t < 16; ++t) {
        unsigned int ew = __shfl((int)egp[t >> 2], ((t & 3) << 4) + m);

        // input B-fragment: B[k = q*8+j][n = read m]
        bf16x8 bin;
        if (q < 2) {
            f32x4 u0 = xa[t & 1][0];
            f32x4 u1 = xa[t & 1][1];
            bin[0] = (__bf16)u0[0]; bin[1] = (__bf16)u0[1];
            bin[2] = (__bf16)u0[2]; bin[3] = (__bf16)u0[3];
            bin[4] = (__bf16)u1[0]; bin[5] = (__bf16)u1[1];
            bin[6] = (__bf16)u1[2]; bin[7] = (__bf16)u1[3];
        } else if (q == 2) {
            unsigned short lo = (unsigned short)(ew & 0xffffu);
            unsigned short hi = (unsigned short)(ew >> 16);
            __bf16 bx, by;
            __builtin_memcpy(&bx, &lo, 2);
            __builtin_memcpy(&by, &hi, 2);
            bin[0] = bx; bin[1] = by;
            bin[2] = (__bf16)1.0f;   // bias-1 input at k==18
            bin[3] = (__bf16)0.f; bin[4] = (__bf16)0.f;
            bin[5] = (__bf16)0.f; bin[6] = (__bf16)0.f; bin[7] = (__bf16)0.f;
        } else {
#pragma unroll
            for (int j = 0; j < 8; ++j) bin[j] = (__bf16)0.f;
        }

        // refill this ring slot with tile t+2 (loads overlap the MFMAs)
        if (t < 14) issueTile(t + 2);

        // layer1 (A-frags streamed from LDS) -> relu/pack -> layer2 (regs)
        f32x4 c2a = zero, c2b = zero;
#pragma unroll
        for (int kt = 0; kt < 5; ++kt) {
            bf16x8 fa = *(const bf16x8*)(fL1 + (2 * kt)     * 1024 + lofs);
            bf16x8 fbb= *(const bf16x8*)(fL1 + (2 * kt + 1) * 1024 + lofs);
            f32x4 ca = __builtin_amdgcn_mfma_f32_16x16x32_bf16(fa,  bin, zero, 0, 0, 0);
            f32x4 cb = __builtin_amdgcn_mfma_f32_16x16x32_bf16(fbb, bin, zero, 0, 0, 0);
            bf16x8 bh;
            bh[0] = (__bf16)fmaxf(ca[0], 0.f); bh[1] = (__bf16)fmaxf(ca[1], 0.f);
            bh[2] = (__bf16)fmaxf(ca[2], 0.f); bh[3] = (__bf16)fmaxf(ca[3], 0.f);
            bh[4] = (__bf16)fmaxf(cb[0], 0.f); bh[5] = (__bf16)fmaxf(cb[1], 0.f);
            bh[6] = (__bf16)fmaxf(cb[2], 0.f); bh[7] = (__bf16)fmaxf(cb[3], 0.f);
            if (kt == 4 && q == 2) bh[6] = (__bf16)1.0f;   // bias row k==150
            if (kt & 1) c2b = __builtin_amdgcn_mfma_f32_16x16x32_bf16(fr2[kt], bh, c2b, 0, 0, 0);
            else        c2a = __builtin_amdgcn_mfma_f32_16x16x32_bf16(fr2[kt], bh, c2a, 0, 0, 0);
        }

        // h -> LDS (never touches HBM); b2 folded via bias row
        if (q < 2) {
            int br   = wv * 256 + t * 16 + m;    // block read idx
            int site = br >> 5, mm = br & 31;
            bf16x4 o;
            o[0] = (__bf16)fmaxf(c2a[0] + c2b[0], 0.f);
            o[1] = (__bf16)fmaxf(c2a[1] + c2b[1], 0.f);
            o[2] = (__bf16)fmaxf(c2a[2] + c2b[2], 0.f);
            o[3] = (__bf16)fmaxf(c2a[3] + c2b[3], 0.f);
            *(bf16x4*)(sH + site * 264 + mm * 8 + q * 4) = o;
        }
    }
    __syncthreads();   // bar3: MLP done; L1 tiles dead -> sAgg region free

    float* sAgg = (float*)(smem + AGG_OFF);
    float* sPart= (float*)(smem + PART_OFF);

    // ---- per-(site,p) aggregation: stats + sort16x2 + halver merge ----
    const int sg = tid >> 3, p = tid & 7;
    {
        float va[16], vb[16];
        float sum = 0.f, sumsq = 0.f;
#pragma unroll
        for (int mm = 0; mm < 16; ++mm) {
            float v1 = (float)sH[sg * 264 + mm * 8 + p];
            float v2 = (float)sH[sg * 264 + (16 + mm) * 8 + p];
            va[mm] = v1; vb[mm] = v2;
            sum += v1 + v2;
            sumsq = fmaf(v1, v1, sumsq);
            sumsq = fmaf(v2, v2, sumsq);
        }
        sort16(va);
        sort16(vb);
        float mn = fminf(va[0], vb[0]);
        float mx = fmaxf(va[15], vb[15]);
        // lower median of 32 = max_i min(a[i], b[15-i])  (bitonic halver)
        float med = fminf(va[0], vb[15]);
#pragma unroll
        for (int i = 1; i < 16; ++i) med = fmaxf(med, fminf(va[i], vb[15 - i]));
        float mean = sum * (1.f / 32.f);
        float var  = fmaxf((sumsq - 32.f * mean * mean) * (1.f / 31.f), 0.f);
        sAgg[sg * 44 + 0 * 8 + p] = mean;
        sAgg[sg * 44 + 1 * 8 + p] = var;
        sAgg[sg * 44 + 2 * 8 + p] = mn;
        sAgg[sg * 44 + 3 * 8 + p] = med;
        sAgg[sg * 44 + 4 * 8 + p] = mx;
    }
    __syncthreads();   // bar4: sH dead -> stage W3 (bf16) at base

    // ---- phase D: stage W3 as bf16 (+b3/W4 f32) ----
    __bf16* sW3b = (__bf16*)smem;                // 6000 bf16 = 12000 B
    float*  sB3  = (float*)(smem + B3_OFF);
    float*  sW4  = (float*)(smem + W4_OFF);
    for (int e = tid; e < 6000; e += 256) sW3b[e] = (__bf16)W3[e];
    if (tid < 160) {
        sB3[tid] = (tid < HDIM) ? b3[tid] : 0.f;
        sW4[tid] = (tid < HDIM) ? W4[tid] : 0.f;
    }
    __syncthreads();   // bar5

    // head A-fragment: tile (jt,kc): A[row=jt*16+m][k=kc*32+q*8+j] = W3[k][row]
    const int jthalf = wv >> 1, sh = wv & 1;
    uint4 HF[10];
#pragma unroll
    for (int i = 0; i < 10; ++i) {
        int jt = jthalf * 5 + (i >> 1), kc = i & 1;
        int row = jt * 16 + m;
        unsigned int w[4];
#pragma unroll
        for (int dw = 0; dw < 4; ++dw) {
            int k0 = kc * 32 + q * 8 + dw * 2, k1 = k0 + 1;
            unsigned short u0 = 0, u1 = 0;
            if (row < HDIM) {
                if (k0 < 40) __builtin_memcpy(&u0, &sW3b[k0 * HDIM + row], 2);
                if (k1 < 40) __builtin_memcpy(&u1, &sW3b[k1 * HDIM + row], 2);
            }
            w[dw] = (unsigned int)u0 | ((unsigned int)u1 << 16);
        }
        HF[i] = make_uint4(w[0], w[1], w[2], w[3]);
    }
    const bf16x8* hf = (const bf16x8*)HF;

    // ---- head MLP via MFMA: Z[j][site] = W3^T @ AGG, wave = (jthalf, sh) ----
    // B-frag: lane(m,q) holds AGG[k = kc*32+q*8+j][site sh*16+m], split hi/lo
    const int site = sh * 16 + m;
    const float* ar = sAgg + site * 44;
    bf16x8 bh0, bl0, bh1, bl1;
    {
        float4 a0 = *(const float4*)(ar + q * 8);
        float4 a1 = *(const float4*)(ar + q * 8 + 4);
        float va[8] = {a0.x, a0.y, a0.z, a0.w, a1.x, a1.y, a1.z, a1.w};
#pragma unroll
        for (int j = 0; j < 8; ++j) {
            __bf16 hi = (__bf16)va[j];
            bh0[j] = hi;
            bl0[j] = (__bf16)(va[j] - (float)hi);
        }
    }
    if (q == 0) {       // kc=1 covers k = 32..39 (stat 4); other q are zero
        float4 a0 = *(const float4*)(ar + 32);
        float4 a1 = *(const float4*)(ar + 36);
        float va[8] = {a0.x, a0.y, a0.z, a0.w, a1.x, a1.y, a1.z, a1.w};
#pragma unroll
        for (int j = 0; j < 8; ++j) {
            __bf16 hi = (__bf16)va[j];
            bh1[j] = hi;
            bl1[j] = (__bf16)(va[j] - (float)hi);
        }
    } else {
#pragma unroll
        for (int j = 0; j < 8; ++j) { bh1[j] = (__bf16)0.f; bl1[j] = (__bf16)0.f; }
    }

    const float4* b3v = (const float4*)sB3;
    const float4* w4v = (const float4*)sW4;
    float sacc = 0.f;
#pragma unroll
    for (int jj = 0; jj < 5; ++jj) {
        int jt = jthalf * 5 + jj;
        float4 bi = b3v[jt * 4 + q];             // rows jt*16+q*4 .. +3
        f32x4 acc = {bi.x, bi.y, bi.z, bi.w};
        acc = __builtin_amdgcn_mfma_f32_16x16x32_bf16(hf[jj * 2 + 0], bh0, acc, 0, 0, 0);
        acc = __builtin_amdgcn_mfma_f32_16x16x32_bf16(hf[jj * 2 + 0], bl0, acc, 0, 0, 0);
        acc = __builtin_amdgcn_mfma_f32_16x16x32_bf16(hf[jj * 2 + 1], bh1, acc, 0, 0, 0);
        acc = __builtin_amdgcn_mfma_f32_16x16x32_bf16(hf[jj * 2 + 1], bl1, acc, 0, 0, 0);
        float4 w4q = w4v[jt * 4 + q];
        sacc = fmaf(fmaxf(acc[0], 0.f), w4q.x, sacc);
        sacc = fmaf(fmaxf(acc[1], 0.f), w4q.y, sacc);
        sacc = fmaf(fmaxf(acc[2], 0.f), w4q.z, sacc);
        sacc = fmaf(fmaxf(acc[3], 0.f), w4q.w, sacc);
    }
    // reduce over the 4 q row-groups (j within tile), then across jthalf waves
    sacc += __shfl_xor(sacc, 16);
    sacc += __shfl_xor(sacc, 32);
    if (jthalf == 1 && lane < 16) sPart[sh * 16 + lane] = sacc;
    __syncthreads();   // bar6
    if (jthalf == 0 && lane < 16) {
        int s2 = sh * 16 + lane;
        float zf = sacc + sPart[s2] + b4[0];
        if (gblk + s2 < Gtot) out[gblk + s2] = 1.f / (1.f + expf(-zf));
    }
}

// ---------------------------------------------------------------------------
extern "C" void kernel_launch(void* const* d_in, const int* in_sizes, int n_in,
                              void* d_out, int out_size, void* d_ws, size_t ws_size,
                              hipStream_t stream) {
    const float* x       = (const float*)d_in[0];
    const int*   kmer    = (const int*)  d_in[1];
    const int*   indices = (const int*)  d_in[2];
    const float* emb     = (const float*)d_in[3];
    const float* W1      = (const float*)d_in[4];
    const float* b1      = (const float*)d_in[5];
    const float* W2      = (const float*)d_in[6];
    const float* b2      = (const float*)d_in[7];
    const float* W3      = (const float*)d_in[8];
    const float* b3      = (const float*)d_in[9];
    const float* W4      = (const float*)d_in[10];
    const float* b4      = (const float*)d_in[11];

    float* out = (float*)d_out;
    const int G = out_size;

    const int grid = (G + 31) / 32;              // 32 sites / block
    k_all<<<grid, 256, 0, stream>>>(x, kmer, indices, emb,
                                    W1, b1, W2, b2, W3, b3, W4, b4,
                                    out, G);
}

// Round 10
// 45.824 us; speedup vs baseline: 3.5411x; 1.0085x over previous
//
#include <hip/hip_runtime.h>
#include <hip/hip_bf16.h>
#include <math.h>

#define HDIM 150

typedef __bf16 bf16x8 __attribute__((ext_vector_type(8)));
typedef __bf16 bf16x4 __attribute__((ext_vector_type(4)));
typedef float  f32x4  __attribute__((ext_vector_type(4)));

// ---------------------------------------------------------------------------
// fully unrolled Batcher odd-even mergesort, n = 16
// ---------------------------------------------------------------------------
__device__ __forceinline__ void cswap(float& a, float& b) {
    float lo = fminf(a, b);
    float hi = fmaxf(a, b);
    a = lo; b = hi;
}

__device__ __forceinline__ void sort16(float v[16]) {
#pragma unroll
    for (int pp = 1; pp < 16; pp <<= 1) {
#pragma unroll
        for (int k = pp; k >= 1; k >>= 1) {
#pragma unroll
            for (int j = k & (pp - 1); j + k < 16; j += 2 * k) {
#pragma unroll
                for (int i = 0; i < k; ++i) {
                    if ((i + j) / (2 * pp) == (i + j + k) / (2 * pp))
                        cswap(v[i + j], v[i + j + k]);
                }
            }
        }
    }
}

// ---------------------------------------------------------------------------
// k_all R18: R17 structure, stall-reduction pass.
// R17 post-mortem: 5-wave cap bought nothing (occupancy avg is skew-limited,
// not allocation-limited); all pipes <15% per-SIMD -> stall-dominated.
//  * launch_bounds back to (256,4): the 5th wave never materialized; the
//    96-reg cap only constrained the scheduler.
//  * 4-deep x register ring (xa[4][2]): ~8 loads in flight, 2x latency cover
//    of the 2-deep ring. Fits at the 128-reg budget.
//  * T14 async-stage for W3/b3/W4: global->reg loads issued right after bar3,
//    L2 latency hides under the agg phase; LDS writes after bar4. Removes the
//    serialized load phase between bar4 and bar5.
// L1 A-fragments stay in LDS (R17); layer-2 frags + b2-folding unchanged.
//
// LDS overlay (32256 B):
//   [0,16200)      phase A: W1|b1@2700|W2@2850 staging (f32)
//   [0,16896)      phase B: sH (32*264 bf16)       [after bar2]
//   [0,12000)      phase D: W3 staging (bf16)      [after bar4]
//   [16896,32256)  phase A/B: frag blob, 15 tiles x 1KB
//   [16896,22528)  phase C: sAgg (32*44 f32)       [after bar3; L1 tiles dead]
//   [22528,23168)  sB3 | [23168,23808) sW4 | [23808,23936) sPart
// ---------------------------------------------------------------------------
#define FB_OFF     16896                 // frag blob base
#define AGG_OFF    16896                 // sAgg overlays L1 tiles after bar3
#define B3_OFF     22528
#define W4_OFF     23168
#define PART_OFF   23808
#define SMEM_TOTAL 32256

__global__ __launch_bounds__(256, 4) void k_all(
    const float* __restrict__ x, const int* __restrict__ kmer,
    const int* __restrict__ indices, const float* __restrict__ emb,
    const float* __restrict__ W1, const float* __restrict__ b1,
    const float* __restrict__ W2, const float* __restrict__ b2,
    const float* __restrict__ W3, const float* __restrict__ b3,
    const float* __restrict__ W4, const float* __restrict__ b4,
    float* __restrict__ out, int Gtot)
{
    __shared__ __align__(16) char smem[SMEM_TOTAL];

    const int tid  = threadIdx.x;
    const int lane = tid & 63;
    const int wv   = tid >> 6;
    const int m    = lane & 15;
    const int q    = lane >> 4;

    const int gblk  = blockIdx.x * 32;           // first site of this block
    const int rbase = gblk * 32;                 // first flat read-slot

    // ---- read indices + emb chain (4 groups of 64 reads per wave) ----
    int          rg[4];
    unsigned int egp[4];                         // packed bf16 (ex,ey)
    {
        const int lim = Gtot * 32 - 1;
#pragma unroll
        for (int g = 0; g < 4; ++g) {
            int fl = rbase + wv * 256 + g * 64 + lane;
            rg[g] = indices[fl > lim ? lim : fl];
        }
        int kk[4];
#pragma unroll
        for (int g = 0; g < 4; ++g) kk[g] = kmer[rg[g]];
        const float2* emb2 = (const float2*)emb;
#pragma unroll
        for (int g = 0; g < 4; ++g) {
            float2 e = emb2[kk[g]];
            __bf16 bx = (__bf16)e.x, by = (__bf16)e.y;
            unsigned short ux, uy;
            __builtin_memcpy(&ux, &bx, 2);
            __builtin_memcpy(&uy, &by, 2);
            egp[g] = (unsigned int)ux | ((unsigned int)uy << 16);
        }
    }

    // ---- phase A: stage W1|b1|W2, build fragment blob in LDS ----
    float* sWgt = (float*)smem;                  // [0,16200) bytes as f32
    for (int e = tid; e < 2700; e += 256) sWgt[e] = W1[e];
    for (int e = tid; e < 150;  e += 256) sWgt[2700 + e] = b1[e];
    for (int e = tid; e < 1200; e += 256) sWgt[2850 + e] = W2[e];
    __syncthreads();                             // bar1

    unsigned int* fb = (unsigned int*)(smem + FB_OFF);
    {
        const int c = tid >> 6;                  // dword chunk 0..3
        for (int d = c * 15; d < c * 15 + 15; ++d) {
            float v0 = 0.f, v1 = 0.f;
            if (d < 40) {
                int n = d >> 2, j0 = (d & 3) * 2;
                // permuted hidden rows for the register relay:
                //   tile 2kt   row(4q+r) = hidden 32kt+8q+r
                //   tile 2kt+1 row(4q+r) = hidden 32kt+8q+4+r
                int hid = 32 * (n >> 1) + 8 * (m >> 2) + 4 * (n & 1) + (m & 3);
                if (hid < HDIM) {
                    int k0 = q * 8 + j0, k1 = k0 + 1;
                    v0 = (k0 < 18) ? sWgt[k0 * HDIM + hid] : (k0 == 18 ? sWgt[2700 + hid] : 0.f);
                    v1 = (k1 < 18) ? sWgt[k1 * HDIM + hid] : (k1 == 18 ? sWgt[2700 + hid] : 0.f);
                }
            } else {
                int kt = (d - 40) >> 2, j0 = ((d - 40) & 3) * 2;
                int k0 = kt * 32 + q * 8 + j0, k1 = k0 + 1;
                if (m < 8) {
                    v0 = (k0 < HDIM) ? sWgt[2850 + k0 * 8 + m]
                                     : (k0 == HDIM ? b2[m] : 0.f);   // b2 row
                    v1 = (k1 < HDIM) ? sWgt[2850 + k1 * 8 + m]
                                     : (k1 == HDIM ? b2[m] : 0.f);
                }
            }
            __bf16 h0 = (__bf16)v0, h1 = (__bf16)v1;
            unsigned short u0, u1;
            __builtin_memcpy(&u0, &h0, 2);
            __builtin_memcpy(&u1, &h1, 2);
            fb[(d >> 2) * 256 + lane * 4 + (d & 3)] =
                (unsigned int)u0 | ((unsigned int)u1 << 16);
        }
    }
    __syncthreads();                             // bar2 (sWgt dead)

    // ---- layer2 fragments (tiles 10..14) pulled into registers ----
    uint4 B2F[5];
    const uint4* fb4 = (const uint4*)fb;
#pragma unroll
    for (int i = 0; i < 5; ++i) B2F[i] = fb4[(10 + i) * 64 + lane];
    const bf16x8* fr2 = (const bf16x8*)B2F;      // fr2[0..4] = layer2 frags

    const char* fL1 = (const char*)fb;           // L1 tiles, read per kt
    const int   lofs = lane * 16;

    const char* xg = (const char*)x;

    // ---- 4-deep register pipeline for the x gather ----
    f32x4 xa[4][2];
    auto issueTile = [&](int t) {
        int rr = __shfl(rg[t >> 2], ((t & 3) << 4) + m);
        if (q < 2) {
            const f32x4* src = (const f32x4*)(xg + (size_t)rr * 64 + (size_t)q * 32);
            xa[t & 3][0] = src[0];
            xa[t & 3][1] = src[1];
        }
    };
    issueTile(0);
    issueTile(1);
    issueTile(2);
    issueTile(3);

    __bf16* sH = (__bf16*)smem;                  // overlays dead sWgt
    const f32x4 zero = {0.f, 0.f, 0.f, 0.f};

#pragma unroll
    for (int t = 0; t < 16; ++t) {
        unsigned int ew = __shfl((int)egp[t >> 2], ((t & 3) << 4) + m);

        // input B-fragment: B[k = q*8+j][n = read m]
        bf16x8 bin;
        if (q < 2) {
            f32x4 u0 = xa[t & 3][0];
            f32x4 u1 = xa[t & 3][1];
            bin[0] = (__bf16)u0[0]; bin[1] = (__bf16)u0[1];
            bin[2] = (__bf16)u0[2]; bin[3] = (__bf16)u0[3];
            bin[4] = (__bf16)u1[0]; bin[5] = (__bf16)u1[1];
            bin[6] = (__bf16)u1[2]; bin[7] = (__bf16)u1[3];
        } else if (q == 2) {
            unsigned short lo = (unsigned short)(ew & 0xffffu);
            unsigned short hi = (unsigned short)(ew >> 16);
            __bf16 bx, by;
            __builtin_memcpy(&bx, &lo, 2);
            __builtin_memcpy(&by, &hi, 2);
            bin[0] = bx; bin[1] = by;
            bin[2] = (__bf16)1.0f;   // bias-1 input at k==18
            bin[3] = (__bf16)0.f; bin[4] = (__bf16)0.f;
            bin[5] = (__bf16)0.f; bin[6] = (__bf16)0.f; bin[7] = (__bf16)0.f;
        } else {
#pragma unroll
            for (int j = 0; j < 8; ++j) bin[j] = (__bf16)0.f;
        }

        // refill this ring slot with tile t+4 (loads overlap the MFMAs)
        if (t < 12) issueTile(t + 4);

        // layer1 (A-frags streamed from LDS) -> relu/pack -> layer2 (regs)
        f32x4 c2a = zero, c2b = zero;
#pragma unroll
        for (int kt = 0; kt < 5; ++kt) {
            bf16x8 fa = *(const bf16x8*)(fL1 + (2 * kt)     * 1024 + lofs);
            bf16x8 fbb= *(const bf16x8*)(fL1 + (2 * kt + 1) * 1024 + lofs);
            f32x4 ca = __builtin_amdgcn_mfma_f32_16x16x32_bf16(fa,  bin, zero, 0, 0, 0);
            f32x4 cb = __builtin_amdgcn_mfma_f32_16x16x32_bf16(fbb, bin, zero, 0, 0, 0);
            bf16x8 bh;
            bh[0] = (__bf16)fmaxf(ca[0], 0.f); bh[1] = (__bf16)fmaxf(ca[1], 0.f);
            bh[2] = (__bf16)fmaxf(ca[2], 0.f); bh[3] = (__bf16)fmaxf(ca[3], 0.f);
            bh[4] = (__bf16)fmaxf(cb[0], 0.f); bh[5] = (__bf16)fmaxf(cb[1], 0.f);
            bh[6] = (__bf16)fmaxf(cb[2], 0.f); bh[7] = (__bf16)fmaxf(cb[3], 0.f);
            if (kt == 4 && q == 2) bh[6] = (__bf16)1.0f;   // bias row k==150
            if (kt & 1) c2b = __builtin_amdgcn_mfma_f32_16x16x32_bf16(fr2[kt], bh, c2b, 0, 0, 0);
            else        c2a = __builtin_amdgcn_mfma_f32_16x16x32_bf16(fr2[kt], bh, c2a, 0, 0, 0);
        }

        // h -> LDS (never touches HBM); b2 folded via bias row
        if (q < 2) {
            int br   = wv * 256 + t * 16 + m;    // block read idx
            int site = br >> 5, mm = br & 31;
            bf16x4 o;
            o[0] = (__bf16)fmaxf(c2a[0] + c2b[0], 0.f);
            o[1] = (__bf16)fmaxf(c2a[1] + c2b[1], 0.f);
            o[2] = (__bf16)fmaxf(c2a[2] + c2b[2], 0.f);
            o[3] = (__bf16)fmaxf(c2a[3] + c2b[3], 0.f);
            *(bf16x4*)(sH + site * 264 + mm * 8 + q * 4) = o;
        }
    }
    __syncthreads();   // bar3: MLP done; L1 tiles dead -> sAgg region free

    float* sAgg = (float*)(smem + AGG_OFF);
    float* sPart= (float*)(smem + PART_OFF);

    // ---- T14 async-stage: issue W3/b3/W4 loads now; agg hides the latency --
    float w3r[24];
#pragma unroll
    for (int i = 0; i < 24; ++i) {
        int e = tid + i * 256;
        w3r[i] = (e < 6000) ? W3[e] : 0.f;
    }
    float b3r = 0.f, w4r = 0.f;
    if (tid < 160) {
        b3r = (tid < HDIM) ? b3[tid] : 0.f;
        w4r = (tid < HDIM) ? W4[tid] : 0.f;
    }

    // ---- per-(site,p) aggregation: stats + sort16x2 + halver merge ----
    const int sg = tid >> 3, p = tid & 7;
    {
        float va[16], vb[16];
        float sum = 0.f, sumsq = 0.f;
#pragma unroll
        for (int mm = 0; mm < 16; ++mm) {
            float v1 = (float)sH[sg * 264 + mm * 8 + p];
            float v2 = (float)sH[sg * 264 + (16 + mm) * 8 + p];
            va[mm] = v1; vb[mm] = v2;
            sum += v1 + v2;
            sumsq = fmaf(v1, v1, sumsq);
            sumsq = fmaf(v2, v2, sumsq);
        }
        sort16(va);
        sort16(vb);
        float mn = fminf(va[0], vb[0]);
        float mx = fmaxf(va[15], vb[15]);
        // lower median of 32 = max_i min(a[i], b[15-i])  (bitonic halver)
        float med = fminf(va[0], vb[15]);
#pragma unroll
        for (int i = 1; i < 16; ++i) med = fmaxf(med, fminf(va[i], vb[15 - i]));
        float mean = sum * (1.f / 32.f);
        float var  = fmaxf((sumsq - 32.f * mean * mean) * (1.f / 31.f), 0.f);
        sAgg[sg * 44 + 0 * 8 + p] = mean;
        sAgg[sg * 44 + 1 * 8 + p] = var;
        sAgg[sg * 44 + 2 * 8 + p] = mn;
        sAgg[sg * 44 + 3 * 8 + p] = med;
        sAgg[sg * 44 + 4 * 8 + p] = mx;
    }
    __syncthreads();   // bar4: sH dead -> write staged W3 (bf16) at base

    // ---- phase D: write staged W3 as bf16 (+b3/W4 f32) ----
    __bf16* sW3b = (__bf16*)smem;                // 6000 bf16 = 12000 B
    float*  sB3  = (float*)(smem + B3_OFF);
    float*  sW4  = (float*)(smem + W4_OFF);
#pragma unroll
    for (int i = 0; i < 24; ++i) {
        int e = tid + i * 256;
        if (e < 6000) sW3b[e] = (__bf16)w3r[i];
    }
    if (tid < 160) { sB3[tid] = b3r; sW4[tid] = w4r; }
    __syncthreads();   // bar5

    // head A-fragment: tile (jt,kc): A[row=jt*16+m][k=kc*32+q*8+j] = W3[k][row]
    const int jthalf = wv >> 1, sh = wv & 1;
    uint4 HF[10];
#pragma unroll
    for (int i = 0; i < 10; ++i) {
        int jt = jthalf * 5 + (i >> 1), kc = i & 1;
        int row = jt * 16 + m;
        unsigned int w[4];
#pragma unroll
        for (int dw = 0; dw < 4; ++dw) {
            int k0 = kc * 32 + q * 8 + dw * 2, k1 = k0 + 1;
            unsigned short u0 = 0, u1 = 0;
            if (row < HDIM) {
                if (k0 < 40) __builtin_memcpy(&u0, &sW3b[k0 * HDIM + row], 2);
                if (k1 < 40) __builtin_memcpy(&u1, &sW3b[k1 * HDIM + row], 2);
            }
            w[dw] = (unsigned int)u0 | ((unsigned int)u1 << 16);
        }
        HF[i] = make_uint4(w[0], w[1], w[2], w[3]);
    }
    const bf16x8* hf = (const bf16x8*)HF;

    // ---- head MLP via MFMA: Z[j][site] = W3^T @ AGG, wave = (jthalf, sh) ----
    // B-frag: lane(m,q) holds AGG[k = kc*32+q*8+j][site sh*16+m], split hi/lo
    const int site = sh * 16 + m;
    const float* ar = sAgg + site * 44;
    bf16x8 bh0, bl0, bh1, bl1;
    {
        float4 a0 = *(const float4*)(ar + q * 8);
        float4 a1 = *(const float4*)(ar + q * 8 + 4);
        float va[8] = {a0.x, a0.y, a0.z, a0.w, a1.x, a1.y, a1.z, a1.w};
#pragma unroll
        for (int j = 0; j < 8; ++j) {
            __bf16 hi = (__bf16)va[j];
            bh0[j] = hi;
            bl0[j] = (__bf16)(va[j] - (float)hi);
        }
    }
    if (q == 0) {       // kc=1 covers k = 32..39 (stat 4); other q are zero
        float4 a0 = *(const float4*)(ar + 32);
        float4 a1 = *(const float4*)(ar + 36);
        float va[8] = {a0.x, a0.y, a0.z, a0.w, a1.x, a1.y, a1.z, a1.w};
#pragma unroll
        for (int j = 0; j < 8; ++j) {
            __bf16 hi = (__bf16)va[j];
            bh1[j] = hi;
            bl1[j] = (__bf16)(va[j] - (float)hi);
        }
    } else {
#pragma unroll
        for (int j = 0; j < 8; ++j) { bh1[j] = (__bf16)0.f; bl1[j] = (__bf16)0.f; }
    }

    const float4* b3v = (const float4*)sB3;
    const float4* w4v = (const float4*)sW4;
    float sacc = 0.f;
#pragma unroll
    for (int jj = 0; jj < 5; ++jj) {
        int jt = jthalf * 5 + jj;
        float4 bi = b3v[jt * 4 + q];             // rows jt*16+q*4 .. +3
        f32x4 acc = {bi.x, bi.y, bi.z, bi.w};
        acc = __builtin_amdgcn_mfma_f32_16x16x32_bf16(hf[jj * 2 + 0], bh0, acc, 0, 0, 0);
        acc = __builtin_amdgcn_mfma_f32_16x16x32_bf16(hf[jj * 2 + 0], bl0, acc, 0, 0, 0);
        acc = __builtin_amdgcn_mfma_f32_16x16x32_bf16(hf[jj * 2 + 1], bh1, acc, 0, 0, 0);
        acc = __builtin_amdgcn_mfma_f32_16x16x32_bf16(hf[jj * 2 + 1], bl1, acc, 0, 0, 0);
        float4 w4q = w4v[jt * 4 + q];
        sacc = fmaf(fmaxf(acc[0], 0.f), w4q.x, sacc);
        sacc = fmaf(fmaxf(acc[1], 0.f), w4q.y, sacc);
        sacc = fmaf(fmaxf(acc[2], 0.f), w4q.z, sacc);
        sacc = fmaf(fmaxf(acc[3], 0.f), w4q.w, sacc);
    }
    // reduce over the 4 q row-groups (j within tile), then across jthalf waves
    sacc += __shfl_xor(sacc, 16);
    sacc += __shfl_xor(sacc, 32);
    if (jthalf == 1 && lane < 16) sPart[sh * 16 + lane] = sacc;
    __syncthreads();   // bar6
    if (jthalf == 0 && lane < 16) {
        int s2 = sh * 16 + lane;
        float zf = sacc + sPart[s2] + b4[0];
        if (gblk + s2 < Gtot) out[gblk + s2] = 1.f / (1.f + expf(-zf));
    }
}

// ---------------------------------------------------------------------------
extern "C" void kernel_launch(void* const* d_in, const int* in_sizes, int n_in,
                              void* d_out, int out_size, void* d_ws, size_t ws_size,
                              hipStream_t stream) {
    const float* x       = (const float*)d_in[0];
    const int*   kmer    = (const int*)  d_in[1];
    const int*   indices = (const int*)  d_in[2];
    const float* emb     = (const float*)d_in[3];
    const float* W1      = (const float*)d_in[4];
    const float* b1      = (const float*)d_in[5];
    const float* W2      = (const float*)d_in[6];
    const float* b2      = (const float*)d_in[7];
    const float* W3      = (const float*)d_in[8];
    const float* b3      = (const float*)d_in[9];
    const float* W4      = (const float*)d_in[10];
    const float* b4      = (const float*)d_in[11];

    float* out = (float*)d_out;
    const int G = out_size;

    const int grid = (G + 31) / 32;              // 32 sites / block
    k_all<<<grid, 256, 0, stream>>>(x, kmer, indices, emb,
                                    W1, b1, W2, b2, W3, b3, W4, b4,
                                    out, G);
}

// Round 12
// 38.409 us; speedup vs baseline: 4.2248x; 1.1931x over previous
//
#include <hip/hip_runtime.h>
#include <hip/hip_bf16.h>
#include <hip/hip_fp16.h>
#include <math.h>

#define HDIM 150

typedef __bf16   bf16x8 __attribute__((ext_vector_type(8)));
typedef __fp16   f16x8  __attribute__((ext_vector_type(8)));   // matches builtin 'h'
typedef __fp16   f16x2  __attribute__((ext_vector_type(2)));
typedef float    f32x4  __attribute__((ext_vector_type(4)));

__device__ __forceinline__ unsigned int pk16(float a, float b) {
    f16x2 p = __builtin_amdgcn_cvt_pkrtz(a, b);
    unsigned int w; __builtin_memcpy(&w, &p, 4);
    return w;
}

// ---------------------------------------------------------------------------
// fully unrolled Batcher odd-even mergesort, n = 16
// ---------------------------------------------------------------------------
__device__ __forceinline__ void cswap(float& a, float& b) {
    float lo = fminf(a, b);
    float hi = fmaxf(a, b);
    a = lo; b = hi;
}

__device__ __forceinline__ void sort16(float v[16]) {
#pragma unroll
    for (int pp = 1; pp < 16; pp <<= 1) {
#pragma unroll
        for (int k = pp; k >= 1; k >>= 1) {
#pragma unroll
            for (int j = k & (pp - 1); j + k < 16; j += 2 * k) {
#pragma unroll
                for (int i = 0; i < k; ++i) {
                    if ((i + j) / (2 * pp) == (i + j + k) / (2 * pp))
                        cswap(v[i + j], v[i + j + k]);
                }
            }
        }
    }
}

// ---------------------------------------------------------------------------
// k_all R20: R19 instruction-diet pass, compile-fixed (__fp16 vectors — the
// AMDGPU builtins cvt_pkrtz / mfma_*_f16 are declared over __fp16, not
// _Float16; mixing the two is a hard error).
//  * f16 hidden path (was bf16): mfma_f32_16x16x32_f16 (same rate/geometry),
//    f32->f16 via packed v_cvt_pkrtz (1 op/2 elems), relu via packed max
//    (1 op/2 elems). Relay relu+repack ~20 ops/kt -> 8. Precision improves
//    (f16 10-bit mantissa > bf16 7-bit; |values| small, no range risk).
//  * blob build: thread owns whole tiles -> ds_write_b128 (4x fewer writes,
//    kills the 8-way lane*4-dword write conflicts).
//  * sH row stride 268 elems (dword stride 134 = 6 mod 32): agg reads spread
//    to <=2-way banks; 8B alignment kept.
// Head MFMA stays bf16 (tiny phase, unchanged).
//
// LDS overlay (32512 B, 4 blocks/CU):
//   [0,16200)      phase A: W1|b1@2700|W2@2850 staging (f32)
//   [0,17152)      phase B: sH (32 x 268 f16)      [after bar2]
//   [0,12000)      phase D: W3 staging (bf16)      [after bar4]
//   [17152,32512)  phase A/B: frag blob, 15 tiles x 1KB (f16 frags)
//   [17152,22784)  phase C: sAgg (32*44 f32)       [after bar3]
//   [22784,23424)  sB3 | [23424,24064) sW4 | [24064,24192) sPart
// ---------------------------------------------------------------------------
#define FB_OFF     17152                 // frag blob base
#define AGG_OFF    17152                 // sAgg overlays L1 tiles after bar3
#define B3_OFF     22784
#define W4_OFF     23424
#define PART_OFF   24064
#define SMEM_TOTAL 32512

__global__ __launch_bounds__(256, 4) void k_all(
    const float* __restrict__ x, const int* __restrict__ kmer,
    const int* __restrict__ indices, const float* __restrict__ emb,
    const float* __restrict__ W1, const float* __restrict__ b1,
    const float* __restrict__ W2, const float* __restrict__ b2,
    const float* __restrict__ W3, const float* __restrict__ b3,
    const float* __restrict__ W4, const float* __restrict__ b4,
    float* __restrict__ out, int Gtot)
{
    __shared__ __align__(16) char smem[SMEM_TOTAL];

    const int tid  = threadIdx.x;
    const int lane = tid & 63;
    const int wv   = tid >> 6;
    const int m    = lane & 15;
    const int q    = lane >> 4;

    const int gblk  = blockIdx.x * 32;           // first site of this block
    const int rbase = gblk * 32;                 // first flat read-slot

    // ---- read indices + emb chain (4 groups of 64 reads per wave) ----
    int          rg[4];
    unsigned int egp[4];                         // packed f16 (ex,ey)
    {
        const int lim = Gtot * 32 - 1;
#pragma unroll
        for (int g = 0; g < 4; ++g) {
            int fl = rbase + wv * 256 + g * 64 + lane;
            rg[g] = indices[fl > lim ? lim : fl];
        }
        int kk[4];
#pragma unroll
        for (int g = 0; g < 4; ++g) kk[g] = kmer[rg[g]];
        const float2* emb2 = (const float2*)emb;
#pragma unroll
        for (int g = 0; g < 4; ++g) {
            float2 e = emb2[kk[g]];
            egp[g] = pk16(e.x, e.y);
        }
    }

    // ---- phase A: stage W1|b1|W2, build f16 fragment blob in LDS ----
    float* sWgt = (float*)smem;                  // [0,16200) bytes as f32
    for (int e = tid; e < 2700; e += 256) sWgt[e] = W1[e];
    for (int e = tid; e < 150;  e += 256) sWgt[2700 + e] = b1[e];
    for (int e = tid; e < 1200; e += 256) sWgt[2850 + e] = W2[e];
    __syncthreads();                             // bar1

    uint4* fb4w = (uint4*)(smem + FB_OFF);
    {
        const int c  = tid >> 6;                 // tile chunk 0..3
        const int tn = (c < 3) ? 4 : 3;          // tiles 0..14
        for (int tt = 0; tt < tn; ++tt) {
            const int tile = c * 4 + tt;
            unsigned int w[4];
#pragma unroll
            for (int dw = 0; dw < 4; ++dw) {
                const int d = tile * 4 + dw;
                float v0 = 0.f, v1 = 0.f;
                if (d < 40) {
                    int n = d >> 2, j0 = (d & 3) * 2;
                    // permuted hidden rows for the register relay:
                    //   tile 2kt   row(4q+r) = hidden 32kt+8q+r
                    //   tile 2kt+1 row(4q+r) = hidden 32kt+8q+4+r
                    int hid = 32 * (n >> 1) + 8 * (m >> 2) + 4 * (n & 1) + (m & 3);
                    if (hid < HDIM) {
                        int k0 = q * 8 + j0, k1 = k0 + 1;
                        v0 = (k0 < 18) ? sWgt[k0 * HDIM + hid] : (k0 == 18 ? sWgt[2700 + hid] : 0.f);
                        v1 = (k1 < 18) ? sWgt[k1 * HDIM + hid] : (k1 == 18 ? sWgt[2700 + hid] : 0.f);
                    }
                } else {
                    int kt = (d - 40) >> 2, j0 = ((d - 40) & 3) * 2;
                    int k0 = kt * 32 + q * 8 + j0, k1 = k0 + 1;
                    if (m < 8) {
                        v0 = (k0 < HDIM) ? sWgt[2850 + k0 * 8 + m]
                                         : (k0 == HDIM ? b2[m] : 0.f);   // b2 row
                        v1 = (k1 < HDIM) ? sWgt[2850 + k1 * 8 + m]
                                         : (k1 == HDIM ? b2[m] : 0.f);
                    }
                }
                w[dw] = pk16(v0, v1);
            }
            fb4w[tile * 64 + lane] = make_uint4(w[0], w[1], w[2], w[3]);
        }
    }
    __syncthreads();                             // bar2 (sWgt dead)

    // ---- layer2 fragments (tiles 10..14) pulled into registers ----
    uint4 B2F[5];
    const uint4* fb4 = (const uint4*)fb4w;
#pragma unroll
    for (int i = 0; i < 5; ++i) B2F[i] = fb4[(10 + i) * 64 + lane];
    const f16x8* fr2 = (const f16x8*)B2F;        // fr2[0..4] = layer2 frags

    const char* fL1 = (const char*)fb4w;         // L1 tiles, read per kt
    const int   lofs = lane * 16;

    const char* xg = (const char*)x;

    // ---- 4-deep register pipeline for the x gather ----
    f32x4 xa[4][2];
    auto issueTile = [&](int t) {
        int rr = __shfl(rg[t >> 2], ((t & 3) << 4) + m);
        if (q < 2) {
            const f32x4* src = (const f32x4*)(xg + (size_t)rr * 64 + (size_t)q * 32);
            xa[t & 3][0] = src[0];
            xa[t & 3][1] = src[1];
        }
    };
    issueTile(0);
    issueTile(1);
    issueTile(2);
    issueTile(3);

    __fp16* sH = (__fp16*)smem;                  // overlays dead sWgt
    const f32x4 zero = {0.f, 0.f, 0.f, 0.f};
    const f16x2 z2 = {};

#pragma unroll
    for (int t = 0; t < 16; ++t) {
        unsigned int ew = __shfl((int)egp[t >> 2], ((t & 3) << 4) + m);

        // input B-fragment: B[k = q*8+j][n = read m]
        f16x8 bin;
#pragma unroll
        for (int j = 0; j < 8; ++j) bin[j] = (__fp16)0.f;
        if (q < 2) {
            f32x4 u0 = xa[t & 3][0];
            f32x4 u1 = xa[t & 3][1];
            f16x2 p0 = __builtin_amdgcn_cvt_pkrtz(u0[0], u0[1]);
            f16x2 p1 = __builtin_amdgcn_cvt_pkrtz(u0[2], u0[3]);
            f16x2 p2 = __builtin_amdgcn_cvt_pkrtz(u1[0], u1[1]);
            f16x2 p3 = __builtin_amdgcn_cvt_pkrtz(u1[2], u1[3]);
            bin[0] = p0[0]; bin[1] = p0[1]; bin[2] = p1[0]; bin[3] = p1[1];
            bin[4] = p2[0]; bin[5] = p2[1]; bin[6] = p3[0]; bin[7] = p3[1];
        } else if (q == 2) {
            f16x2 ep; __builtin_memcpy(&ep, &ew, 4);
            bin[0] = ep[0]; bin[1] = ep[1];
            bin[2] = (__fp16)1.0f;   // bias-1 input at k==18
        }

        // refill this ring slot with tile t+4 (loads overlap the MFMAs)
        if (t < 12) issueTile(t + 4);

        // layer1 (A-frags streamed from LDS) -> packed relu -> layer2 (regs)
        f32x4 c2a = zero, c2b = zero;
#pragma unroll
        for (int kt = 0; kt < 5; ++kt) {
            f16x8 fa = *(const f16x8*)(fL1 + (2 * kt)     * 1024 + lofs);
            f16x8 fbb= *(const f16x8*)(fL1 + (2 * kt + 1) * 1024 + lofs);
            f32x4 ca = __builtin_amdgcn_mfma_f32_16x16x32_f16(fa,  bin, zero, 0, 0, 0);
            f32x4 cb = __builtin_amdgcn_mfma_f32_16x16x32_f16(fbb, bin, zero, 0, 0, 0);
            f16x2 h01 = __builtin_elementwise_max(__builtin_amdgcn_cvt_pkrtz(ca[0], ca[1]), z2);
            f16x2 h23 = __builtin_elementwise_max(__builtin_amdgcn_cvt_pkrtz(ca[2], ca[3]), z2);
            f16x2 h45 = __builtin_elementwise_max(__builtin_amdgcn_cvt_pkrtz(cb[0], cb[1]), z2);
            f16x2 h67 = __builtin_elementwise_max(__builtin_amdgcn_cvt_pkrtz(cb[2], cb[3]), z2);
            f16x8 bh;
            bh[0] = h01[0]; bh[1] = h01[1]; bh[2] = h23[0]; bh[3] = h23[1];
            bh[4] = h45[0]; bh[5] = h45[1]; bh[6] = h67[0]; bh[7] = h67[1];
            if (kt == 4 && q == 2) bh[6] = (__fp16)1.0f;   // bias row k==150
            if (kt & 1) c2b = __builtin_amdgcn_mfma_f32_16x16x32_f16(fr2[kt], bh, c2b, 0, 0, 0);
            else        c2a = __builtin_amdgcn_mfma_f32_16x16x32_f16(fr2[kt], bh, c2a, 0, 0, 0);
        }

        // h -> LDS (never touches HBM); b2 folded via bias row
        if (q < 2) {
            int br   = wv * 256 + t * 16 + m;    // block read idx
            int site = br >> 5, mm = br & 31;
            float s0 = c2a[0] + c2b[0], s1 = c2a[1] + c2b[1];
            float s2 = c2a[2] + c2b[2], s3 = c2a[3] + c2b[3];
            f16x2 o01 = __builtin_elementwise_max(__builtin_amdgcn_cvt_pkrtz(s0, s1), z2);
            f16x2 o23 = __builtin_elementwise_max(__builtin_amdgcn_cvt_pkrtz(s2, s3), z2);
            unsigned int w0, w1;
            __builtin_memcpy(&w0, &o01, 4);
            __builtin_memcpy(&w1, &o23, 4);
            *(uint2*)(sH + site * 268 + mm * 8 + q * 4) = make_uint2(w0, w1);
        }
    }
    __syncthreads();   // bar3: MLP done; L1 tiles dead -> sAgg region free

    float* sAgg = (float*)(smem + AGG_OFF);
    float* sPart= (float*)(smem + PART_OFF);

    // ---- T14 async-stage: issue W3/b3/W4 loads now; agg hides the latency --
    float w3r[24];
#pragma unroll
    for (int i = 0; i < 24; ++i) {
        int e = tid + i * 256;
        w3r[i] = (e < 6000) ? W3[e] : 0.f;
    }
    float b3r = 0.f, w4r = 0.f;
    if (tid < 160) {
        b3r = (tid < HDIM) ? b3[tid] : 0.f;
        w4r = (tid < HDIM) ? W4[tid] : 0.f;
    }

    // ---- per-(site,p) aggregation: stats + sort16x2 + halver merge ----
    const int sg = tid >> 3, p = tid & 7;
    {
        float va[16], vb[16];
        float sum = 0.f, sumsq = 0.f;
#pragma unroll
        for (int mm = 0; mm < 16; ++mm) {
            float v1 = (float)sH[sg * 268 + mm * 8 + p];
            float v2 = (float)sH[sg * 268 + (16 + mm) * 8 + p];
            va[mm] = v1; vb[mm] = v2;
            sum += v1 + v2;
            sumsq = fmaf(v1, v1, sumsq);
            sumsq = fmaf(v2, v2, sumsq);
        }
        sort16(va);
        sort16(vb);
        float mn = fminf(va[0], vb[0]);
        float mx = fmaxf(va[15], vb[15]);
        // lower median of 32 = max_i min(a[i], b[15-i])  (bitonic halver)
        float med = fminf(va[0], vb[15]);
#pragma unroll
        for (int i = 1; i < 16; ++i) med = fmaxf(med, fminf(va[i], vb[15 - i]));
        float mean = sum * (1.f / 32.f);
        float var  = fmaxf((sumsq - 32.f * mean * mean) * (1.f / 31.f), 0.f);
        sAgg[sg * 44 + 0 * 8 + p] = mean;
        sAgg[sg * 44 + 1 * 8 + p] = var;
        sAgg[sg * 44 + 2 * 8 + p] = mn;
        sAgg[sg * 44 + 3 * 8 + p] = med;
        sAgg[sg * 44 + 4 * 8 + p] = mx;
    }
    __syncthreads();   // bar4: sH dead -> write staged W3 (bf16) at base

    // ---- phase D: write staged W3 as bf16 (+b3/W4 f32) ----
    __bf16* sW3b = (__bf16*)smem;                // 6000 bf16 = 12000 B
    float*  sB3  = (float*)(smem + B3_OFF);
    float*  sW4  = (float*)(smem + W4_OFF);
#pragma unroll
    for (int i = 0; i < 24; ++i) {
        int e = tid + i * 256;
        if (e < 6000) sW3b[e] = (__bf16)w3r[i];
    }
    if (tid < 160) { sB3[tid] = b3r; sW4[tid] = w4r; }
    __syncthreads();   // bar5

    // head A-fragment: tile (jt,kc): A[row=jt*16+m][k=kc*32+q*8+j] = W3[k][row]
    const int jthalf = wv >> 1, sh = wv & 1;
    uint4 HF[10];
#pragma unroll
    for (int i = 0; i < 10; ++i) {
        int jt = jthalf * 5 + (i >> 1), kc = i & 1;
        int row = jt * 16 + m;
        unsigned int w[4];
#pragma unroll
        for (int dw = 0; dw < 4; ++dw) {
            int k0 = kc * 32 + q * 8 + dw * 2, k1 = k0 + 1;
            unsigned short u0 = 0, u1 = 0;
            if (row < HDIM) {
                if (k0 < 40) __builtin_memcpy(&u0, &sW3b[k0 * HDIM + row], 2);
                if (k1 < 40) __builtin_memcpy(&u1, &sW3b[k1 * HDIM + row], 2);
            }
            w[dw] = (unsigned int)u0 | ((unsigned int)u1 << 16);
        }
        HF[i] = make_uint4(w[0], w[1], w[2], w[3]);
    }
    const bf16x8* hf = (const bf16x8*)HF;

    // ---- head MLP via MFMA: Z[j][site] = W3^T @ AGG, wave = (jthalf, sh) ----
    // B-frag: lane(m,q) holds AGG[k = kc*32+q*8+j][site sh*16+m], split hi/lo
    const int site = sh * 16 + m;
    const float* ar = sAgg + site * 44;
    bf16x8 bh0, bl0, bh1, bl1;
    {
        float4 a0 = *(const float4*)(ar + q * 8);
        float4 a1 = *(const float4*)(ar + q * 8 + 4);
        float va[8] = {a0.x, a0.y, a0.z, a0.w, a1.x, a1.y, a1.z, a1.w};
#pragma unroll
        for (int j = 0; j < 8; ++j) {
            __bf16 hi = (__bf16)va[j];
            bh0[j] = hi;
            bl0[j] = (__bf16)(va[j] - (float)hi);
        }
    }
    if (q == 0) {       // kc=1 covers k = 32..39 (stat 4); other q are zero
        float4 a0 = *(const float4*)(ar + 32);
        float4 a1 = *(const float4*)(ar + 36);
        float va[8] = {a0.x, a0.y, a0.z, a0.w, a1.x, a1.y, a1.z, a1.w};
#pragma unroll
        for (int j = 0; j < 8; ++j) {
            __bf16 hi = (__bf16)va[j];
            bh1[j] = hi;
            bl1[j] = (__bf16)(va[j] - (float)hi);
        }
    } else {
#pragma unroll
        for (int j = 0; j < 8; ++j) { bh1[j] = (__bf16)0.f; bl1[j] = (__bf16)0.f; }
    }

    const float4* b3v = (const float4*)sB3;
    const float4* w4v = (const float4*)sW4;
    float sacc = 0.f;
#pragma unroll
    for (int jj = 0; jj < 5; ++jj) {
        int jt = jthalf * 5 + jj;
        float4 bi = b3v[jt * 4 + q];             // rows jt*16+q*4 .. +3
        f32x4 acc = {bi.x, bi.y, bi.z, bi.w};
        acc = __builtin_amdgcn_mfma_f32_16x16x32_bf16(hf[jj * 2 + 0], bh0, acc, 0, 0, 0);
        acc = __builtin_amdgcn_mfma_f32_16x16x32_bf16(hf[jj * 2 + 0], bl0, acc, 0, 0, 0);
        acc = __builtin_amdgcn_mfma_f32_16x16x32_bf16(hf[jj * 2 + 1], bh1, acc, 0, 0, 0);
        acc = __builtin_amdgcn_mfma_f32_16x16x32_bf16(hf[jj * 2 + 1], bl1, acc, 0, 0, 0);
        float4 w4q = w4v[jt * 4 + q];
        sacc = fmaf(fmaxf(acc[0], 0.f), w4q.x, sacc);
        sacc = fmaf(fmaxf(acc[1], 0.f), w4q.y, sacc);
        sacc = fmaf(fmaxf(acc[2], 0.f), w4q.z, sacc);
        sacc = fmaf(fmaxf(acc[3], 0.f), w4q.w, sacc);
    }
    // reduce over the 4 q row-groups (j within tile), then across jthalf waves
    sacc += __shfl_xor(sacc, 16);
    sacc += __shfl_xor(sacc, 32);
    if (jthalf == 1 && lane < 16) sPart[sh * 16 + lane] = sacc;
    __syncthreads();   // bar6
    if (jthalf == 0 && lane < 16) {
        int s2 = sh * 16 + lane;
        float zf = sacc + sPart[s2] + b4[0];
        if (gblk + s2 < Gtot) out[gblk + s2] = 1.f / (1.f + expf(-zf));
    }
}

// ---------------------------------------------------------------------------
extern "C" void kernel_launch(void* const* d_in, const int* in_sizes, int n_in,
                              void* d_out, int out_size, void* d_ws, size_t ws_size,
                              hipStream_t stream) {
    const float* x       = (const float*)d_in[0];
    const int*   kmer    = (const int*)  d_in[1];
    const int*   indices = (const int*)  d_in[2];
    const float* emb     = (const float*)d_in[3];
    const float* W1      = (const float*)d_in[4];
    const float* b1      = (const float*)d_in[5];
    const float* W2      = (const float*)d_in[6];
    const float* b2      = (const float*)d_in[7];
    const float* W3      = (const float*)d_in[8];
    const float* b3      = (const float*)d_in[9];
    const float* W4      = (const float*)d_in[10];
    const float* b4      = (const float*)d_in[11];

    float* out = (float*)d_out;
    const int G = out_size;

    const int grid = (G + 31) / 32;              // 32 sites / block
    k_all<<<grid, 256, 0, stream>>>(x, kmer, indices, emb,
                                    W1, b1, W2, b2, W3, b3, W4, b4,
                                    out, G);
}

// Round 13
// 37.110 us; speedup vs baseline: 4.3726x; 1.0350x over previous
//
#include <hip/hip_runtime.h>
#include <hip/hip_bf16.h>
#include <hip/hip_fp16.h>
#include <math.h>

#define HDIM 150

typedef __bf16   bf16x8 __attribute__((ext_vector_type(8)));
typedef __fp16   f16x8  __attribute__((ext_vector_type(8)));   // matches builtin 'h'
typedef __fp16   f16x2  __attribute__((ext_vector_type(2)));
typedef float    f32x4  __attribute__((ext_vector_type(4)));

__device__ __forceinline__ unsigned int pk16(float a, float b) {
    f16x2 p = __builtin_amdgcn_cvt_pkrtz(a, b);
    unsigned int w; __builtin_memcpy(&w, &p, 4);
    return w;
}

// ---------------------------------------------------------------------------
// fully unrolled Batcher odd-even mergesort, n = 16
// ---------------------------------------------------------------------------
__device__ __forceinline__ void cswap(float& a, float& b) {
    float lo = fminf(a, b);
    float hi = fmaxf(a, b);
    a = lo; b = hi;
}

__device__ __forceinline__ void sort16(float v[16]) {
#pragma unroll
    for (int pp = 1; pp < 16; pp <<= 1) {
#pragma unroll
        for (int k = pp; k >= 1; k >>= 1) {
#pragma unroll
            for (int j = k & (pp - 1); j + k < 16; j += 2 * k) {
#pragma unroll
                for (int i = 0; i < k; ++i) {
                    if ((i + j) / (2 * pp) == (i + j + k) / (2 * pp))
                        cswap(v[i + j], v[i + j + k]);
                }
            }
        }
    }
}

// ---------------------------------------------------------------------------
// k_all R21: R20 (f16 diet) + L1 fragments back in REGISTERS.
// R20 post-mortem: diet cut VALU (48->37% busy) and won 7.4us; the new
// dominant serialized resource is LDS bandwidth — streaming L1 frags from
// LDS costs 10 ds_read_b128/tile/wave = 2.56 MB/CU/MLP-phase (~10-12us at
// 85-128 B/cyc). That choice (R17) bought zero occupancy. Revert it:
//  * all 15 blob tiles loaded to regs once after bar2 (60 regs); unified
//    ~115 -> still 4 waves/SIMD, occupancy unchanged, LDS stream gone.
//  * x-ring back to 2-deep (depth was neutral R13..R18; -16 regs insurance
//    against spill).
// Keeps from R20: f16 MFMA path, packed cvt_pkrtz/pk_max relu, b128 blob
// build, sH stride 268.
//
// LDS overlay (32512 B, 4 blocks/CU):
//   [0,16200)      phase A: W1|b1@2700|W2@2850 staging (f32)
//   [0,17152)      phase B: sH (32 x 268 f16)      [after bar2]
//   [0,12000)      phase D: W3 staging (bf16)      [after bar4]
//   [17152,32512)  phase A: frag blob, 15 tiles x 1KB (f16; read once)
//   [17152,22784)  phase C: sAgg (32*44 f32)       [after bar3]
//   [22784,23424)  sB3 | [23424,24064) sW4 | [24064,24192) sPart
// ---------------------------------------------------------------------------
#define FB_OFF     17152                 // frag blob base
#define AGG_OFF    17152                 // sAgg overlays blob after bar3
#define B3_OFF     22784
#define W4_OFF     23424
#define PART_OFF   24064
#define SMEM_TOTAL 32512

__global__ __launch_bounds__(256, 4) void k_all(
    const float* __restrict__ x, const int* __restrict__ kmer,
    const int* __restrict__ indices, const float* __restrict__ emb,
    const float* __restrict__ W1, const float* __restrict__ b1,
    const float* __restrict__ W2, const float* __restrict__ b2,
    const float* __restrict__ W3, const float* __restrict__ b3,
    const float* __restrict__ W4, const float* __restrict__ b4,
    float* __restrict__ out, int Gtot)
{
    __shared__ __align__(16) char smem[SMEM_TOTAL];

    const int tid  = threadIdx.x;
    const int lane = tid & 63;
    const int wv   = tid >> 6;
    const int m    = lane & 15;
    const int q    = lane >> 4;

    const int gblk  = blockIdx.x * 32;           // first site of this block
    const int rbase = gblk * 32;                 // first flat read-slot

    // ---- read indices + emb chain (4 groups of 64 reads per wave) ----
    int          rg[4];
    unsigned int egp[4];                         // packed f16 (ex,ey)
    {
        const int lim = Gtot * 32 - 1;
#pragma unroll
        for (int g = 0; g < 4; ++g) {
            int fl = rbase + wv * 256 + g * 64 + lane;
            rg[g] = indices[fl > lim ? lim : fl];
        }
        int kk[4];
#pragma unroll
        for (int g = 0; g < 4; ++g) kk[g] = kmer[rg[g]];
        const float2* emb2 = (const float2*)emb;
#pragma unroll
        for (int g = 0; g < 4; ++g) {
            float2 e = emb2[kk[g]];
            egp[g] = pk16(e.x, e.y);
        }
    }

    // ---- phase A: stage W1|b1|W2, build f16 fragment blob in LDS ----
    float* sWgt = (float*)smem;                  // [0,16200) bytes as f32
    for (int e = tid; e < 2700; e += 256) sWgt[e] = W1[e];
    for (int e = tid; e < 150;  e += 256) sWgt[2700 + e] = b1[e];
    for (int e = tid; e < 1200; e += 256) sWgt[2850 + e] = W2[e];
    __syncthreads();                             // bar1

    uint4* fb4w = (uint4*)(smem + FB_OFF);
    {
        const int c  = tid >> 6;                 // tile chunk 0..3
        const int tn = (c < 3) ? 4 : 3;          // tiles 0..14
        for (int tt = 0; tt < tn; ++tt) {
            const int tile = c * 4 + tt;
            unsigned int w[4];
#pragma unroll
            for (int dw = 0; dw < 4; ++dw) {
                const int d = tile * 4 + dw;
                float v0 = 0.f, v1 = 0.f;
                if (d < 40) {
                    int n = d >> 2, j0 = (d & 3) * 2;
                    // permuted hidden rows for the register relay:
                    //   tile 2kt   row(4q+r) = hidden 32kt+8q+r
                    //   tile 2kt+1 row(4q+r) = hidden 32kt+8q+4+r
                    int hid = 32 * (n >> 1) + 8 * (m >> 2) + 4 * (n & 1) + (m & 3);
                    if (hid < HDIM) {
                        int k0 = q * 8 + j0, k1 = k0 + 1;
                        v0 = (k0 < 18) ? sWgt[k0 * HDIM + hid] : (k0 == 18 ? sWgt[2700 + hid] : 0.f);
                        v1 = (k1 < 18) ? sWgt[k1 * HDIM + hid] : (k1 == 18 ? sWgt[2700 + hid] : 0.f);
                    }
                } else {
                    int kt = (d - 40) >> 2, j0 = ((d - 40) & 3) * 2;
                    int k0 = kt * 32 + q * 8 + j0, k1 = k0 + 1;
                    if (m < 8) {
                        v0 = (k0 < HDIM) ? sWgt[2850 + k0 * 8 + m]
                                         : (k0 == HDIM ? b2[m] : 0.f);   // b2 row
                        v1 = (k1 < HDIM) ? sWgt[2850 + k1 * 8 + m]
                                         : (k1 == HDIM ? b2[m] : 0.f);
                    }
                }
                w[dw] = pk16(v0, v1);
            }
            fb4w[tile * 64 + lane] = make_uint4(w[0], w[1], w[2], w[3]);
        }
    }
    __syncthreads();                             // bar2 (sWgt dead)

    // ---- ALL 15 fragment tiles pulled into registers (read LDS once) ----
    uint4 B16[15];
    const uint4* fb4 = (const uint4*)fb4w;
#pragma unroll
    for (int i = 0; i < 15; ++i) B16[i] = fb4[i * 64 + lane];
    const f16x8* frv = (const f16x8*)B16;        // frv[0..9]=L1, frv[10..14]=L2

    const char* xg = (const char*)x;

    // ---- 2-tile-deep register pipeline for the x gather ----
    f32x4 xa[2][2];
    auto issueTile = [&](int t) {
        int rr = __shfl(rg[t >> 2], ((t & 3) << 4) + m);
        if (q < 2) {
            const f32x4* src = (const f32x4*)(xg + (size_t)rr * 64 + (size_t)q * 32);
            xa[t & 1][0] = src[0];
            xa[t & 1][1] = src[1];
        }
    };
    issueTile(0);
    issueTile(1);

    __fp16* sH = (__fp16*)smem;                  // overlays dead sWgt
    const f32x4 zero = {0.f, 0.f, 0.f, 0.f};
    const f16x2 z2 = {};

#pragma unroll
    for (int t = 0; t < 16; ++t) {
        unsigned int ew = __shfl((int)egp[t >> 2], ((t & 3) << 4) + m);

        // input B-fragment: B[k = q*8+j][n = read m]
        f16x8 bin;
#pragma unroll
        for (int j = 0; j < 8; ++j) bin[j] = (__fp16)0.f;
        if (q < 2) {
            f32x4 u0 = xa[t & 1][0];
            f32x4 u1 = xa[t & 1][1];
            f16x2 p0 = __builtin_amdgcn_cvt_pkrtz(u0[0], u0[1]);
            f16x2 p1 = __builtin_amdgcn_cvt_pkrtz(u0[2], u0[3]);
            f16x2 p2 = __builtin_amdgcn_cvt_pkrtz(u1[0], u1[1]);
            f16x2 p3 = __builtin_amdgcn_cvt_pkrtz(u1[2], u1[3]);
            bin[0] = p0[0]; bin[1] = p0[1]; bin[2] = p1[0]; bin[3] = p1[1];
            bin[4] = p2[0]; bin[5] = p2[1]; bin[6] = p3[0]; bin[7] = p3[1];
        } else if (q == 2) {
            f16x2 ep; __builtin_memcpy(&ep, &ew, 4);
            bin[0] = ep[0]; bin[1] = ep[1];
            bin[2] = (__fp16)1.0f;   // bias-1 input at k==18
        }

        // refill this ring slot with tile t+2 (loads overlap the MFMAs)
        if (t < 14) issueTile(t + 2);

        // layer1 (reg frags) -> packed relu -> layer2 (reg frags)
        f32x4 c2a = zero, c2b = zero;
#pragma unroll
        for (int kt = 0; kt < 5; ++kt) {
            f32x4 ca = __builtin_amdgcn_mfma_f32_16x16x32_f16(frv[2 * kt],     bin, zero, 0, 0, 0);
            f32x4 cb = __builtin_amdgcn_mfma_f32_16x16x32_f16(frv[2 * kt + 1], bin, zero, 0, 0, 0);
            f16x2 h01 = __builtin_elementwise_max(__builtin_amdgcn_cvt_pkrtz(ca[0], ca[1]), z2);
            f16x2 h23 = __builtin_elementwise_max(__builtin_amdgcn_cvt_pkrtz(ca[2], ca[3]), z2);
            f16x2 h45 = __builtin_elementwise_max(__builtin_amdgcn_cvt_pkrtz(cb[0], cb[1]), z2);
            f16x2 h67 = __builtin_elementwise_max(__builtin_amdgcn_cvt_pkrtz(cb[2], cb[3]), z2);
            f16x8 bh;
            bh[0] = h01[0]; bh[1] = h01[1]; bh[2] = h23[0]; bh[3] = h23[1];
            bh[4] = h45[0]; bh[5] = h45[1]; bh[6] = h67[0]; bh[7] = h67[1];
            if (kt == 4 && q == 2) bh[6] = (__fp16)1.0f;   // bias row k==150
            if (kt & 1) c2b = __builtin_amdgcn_mfma_f32_16x16x32_f16(frv[10 + kt], bh, c2b, 0, 0, 0);
            else        c2a = __builtin_amdgcn_mfma_f32_16x16x32_f16(frv[10 + kt], bh, c2a, 0, 0, 0);
        }

        // h -> LDS (never touches HBM); b2 folded via bias row
        if (q < 2) {
            int br   = wv * 256 + t * 16 + m;    // block read idx
            int site = br >> 5, mm = br & 31;
            float s0 = c2a[0] + c2b[0], s1 = c2a[1] + c2b[1];
            float s2 = c2a[2] + c2b[2], s3 = c2a[3] + c2b[3];
            f16x2 o01 = __builtin_elementwise_max(__builtin_amdgcn_cvt_pkrtz(s0, s1), z2);
            f16x2 o23 = __builtin_elementwise_max(__builtin_amdgcn_cvt_pkrtz(s2, s3), z2);
            unsigned int w0, w1;
            __builtin_memcpy(&w0, &o01, 4);
            __builtin_memcpy(&w1, &o23, 4);
            *(uint2*)(sH + site * 268 + mm * 8 + q * 4) = make_uint2(w0, w1);
        }
    }
    __syncthreads();   // bar3: MLP done; blob reads done -> sAgg region free

    float* sAgg = (float*)(smem + AGG_OFF);
    float* sPart= (float*)(smem + PART_OFF);

    // ---- T14 async-stage: issue W3/b3/W4 loads now; agg hides the latency --
    float w3r[24];
#pragma unroll
    for (int i = 0; i < 24; ++i) {
        int e = tid + i * 256;
        w3r[i] = (e < 6000) ? W3[e] : 0.f;
    }
    float b3r = 0.f, w4r = 0.f;
    if (tid < 160) {
        b3r = (tid < HDIM) ? b3[tid] : 0.f;
        w4r = (tid < HDIM) ? W4[tid] : 0.f;
    }

    // ---- per-(site,p) aggregation: stats + sort16x2 + halver merge ----
    const int sg = tid >> 3, p = tid & 7;
    {
        float va[16], vb[16];
        float sum = 0.f, sumsq = 0.f;
#pragma unroll
        for (int mm = 0; mm < 16; ++mm) {
            float v1 = (float)sH[sg * 268 + mm * 8 + p];
            float v2 = (float)sH[sg * 268 + (16 + mm) * 8 + p];
            va[mm] = v1; vb[mm] = v2;
            sum += v1 + v2;
            sumsq = fmaf(v1, v1, sumsq);
            sumsq = fmaf(v2, v2, sumsq);
        }
        sort16(va);
        sort16(vb);
        float mn = fminf(va[0], vb[0]);
        float mx = fmaxf(va[15], vb[15]);
        // lower median of 32 = max_i min(a[i], b[15-i])  (bitonic halver)
        float med = fminf(va[0], vb[15]);
#pragma unroll
        for (int i = 1; i < 16; ++i) med = fmaxf(med, fminf(va[i], vb[15 - i]));
        float mean = sum * (1.f / 32.f);
        float var  = fmaxf((sumsq - 32.f * mean * mean) * (1.f / 31.f), 0.f);
        sAgg[sg * 44 + 0 * 8 + p] = mean;
        sAgg[sg * 44 + 1 * 8 + p] = var;
        sAgg[sg * 44 + 2 * 8 + p] = mn;
        sAgg[sg * 44 + 3 * 8 + p] = med;
        sAgg[sg * 44 + 4 * 8 + p] = mx;
    }
    __syncthreads();   // bar4: sH dead -> write staged W3 (bf16) at base

    // ---- phase D: write staged W3 as bf16 (+b3/W4 f32) ----
    __bf16* sW3b = (__bf16*)smem;                // 6000 bf16 = 12000 B
    float*  sB3  = (float*)(smem + B3_OFF);
    float*  sW4  = (float*)(smem + W4_OFF);
#pragma unroll
    for (int i = 0; i < 24; ++i) {
        int e = tid + i * 256;
        if (e < 6000) sW3b[e] = (__bf16)w3r[i];
    }
    if (tid < 160) { sB3[tid] = b3r; sW4[tid] = w4r; }
    __syncthreads();   // bar5

    // head A-fragment: tile (jt,kc): A[row=jt*16+m][k=kc*32+q*8+j] = W3[k][row]
    const int jthalf = wv >> 1, sh = wv & 1;
    uint4 HF[10];
#pragma unroll
    for (int i = 0; i < 10; ++i) {
        int jt = jthalf * 5 + (i >> 1), kc = i & 1;
        int row = jt * 16 + m;
        unsigned int w[4];
#pragma unroll
        for (int dw = 0; dw < 4; ++dw) {
            int k0 = kc * 32 + q * 8 + dw * 2, k1 = k0 + 1;
            unsigned short u0 = 0, u1 = 0;
            if (row < HDIM) {
                if (k0 < 40) __builtin_memcpy(&u0, &sW3b[k0 * HDIM + row], 2);
                if (k1 < 40) __builtin_memcpy(&u1, &sW3b[k1 * HDIM + row], 2);
            }
            w[dw] = (unsigned int)u0 | ((unsigned int)u1 << 16);
        }
        HF[i] = make_uint4(w[0], w[1], w[2], w[3]);
    }
    const bf16x8* hf = (const bf16x8*)HF;

    // ---- head MLP via MFMA: Z[j][site] = W3^T @ AGG, wave = (jthalf, sh) ----
    // B-frag: lane(m,q) holds AGG[k = kc*32+q*8+j][site sh*16+m], split hi/lo
    const int site = sh * 16 + m;
    const float* ar = sAgg + site * 44;
    bf16x8 bh0, bl0, bh1, bl1;
    {
        float4 a0 = *(const float4*)(ar + q * 8);
        float4 a1 = *(const float4*)(ar + q * 8 + 4);
        float va[8] = {a0.x, a0.y, a0.z, a0.w, a1.x, a1.y, a1.z, a1.w};
#pragma unroll
        for (int j = 0; j < 8; ++j) {
            __bf16 hi = (__bf16)va[j];
            bh0[j] = hi;
            bl0[j] = (__bf16)(va[j] - (float)hi);
        }
    }
    if (q == 0) {       // kc=1 covers k = 32..39 (stat 4); other q are zero
        float4 a0 = *(const float4*)(ar + 32);
        float4 a1 = *(const float4*)(ar + 36);
        float va[8] = {a0.x, a0.y, a0.z, a0.w, a1.x, a1.y, a1.z, a1.w};
#pragma unroll
        for (int j = 0; j < 8; ++j) {
            __bf16 hi = (__bf16)va[j];
            bh1[j] = hi;
            bl1[j] = (__bf16)(va[j] - (float)hi);
        }
    } else {
#pragma unroll
        for (int j = 0; j < 8; ++j) { bh1[j] = (__bf16)0.f; bl1[j] = (__bf16)0.f; }
    }

    const float4* b3v = (const float4*)sB3;
    const float4* w4v = (const float4*)sW4;
    float sacc = 0.f;
#pragma unroll
    for (int jj = 0; jj < 5; ++jj) {
        int jt = jthalf * 5 + jj;
        float4 bi = b3v[jt * 4 + q];             // rows jt*16+q*4 .. +3
        f32x4 acc = {bi.x, bi.y, bi.z, bi.w};
        acc = __builtin_amdgcn_mfma_f32_16x16x32_bf16(hf[jj * 2 + 0], bh0, acc, 0, 0, 0);
        acc = __builtin_amdgcn_mfma_f32_16x16x32_bf16(hf[jj * 2 + 0], bl0, acc, 0, 0, 0);
        acc = __builtin_amdgcn_mfma_f32_16x16x32_bf16(hf[jj * 2 + 1], bh1, acc, 0, 0, 0);
        acc = __builtin_amdgcn_mfma_f32_16x16x32_bf16(hf[jj * 2 + 1], bl1, acc, 0, 0, 0);
        float4 w4q = w4v[jt * 4 + q];
        sacc = fmaf(fmaxf(acc[0], 0.f), w4q.x, sacc);
        sacc = fmaf(fmaxf(acc[1], 0.f), w4q.y, sacc);
        sacc = fmaf(fmaxf(acc[2], 0.f), w4q.z, sacc);
        sacc = fmaf(fmaxf(acc[3], 0.f), w4q.w, sacc);
    }
    // reduce over the 4 q row-groups (j within tile), then across jthalf waves
    sacc += __shfl_xor(sacc, 16);
    sacc += __shfl_xor(sacc, 32);
    if (jthalf == 1 && lane < 16) sPart[sh * 16 + lane] = sacc;
    __syncthreads();   // bar6
    if (jthalf == 0 && lane < 16) {
        int s2 = sh * 16 + lane;
        float zf = sacc + sPart[s2] + b4[0];
        if (gblk + s2 < Gtot) out[gblk + s2] = 1.f / (1.f + expf(-zf));
    }
}

// ---------------------------------------------------------------------------
extern "C" void kernel_launch(void* const* d_in, const int* in_sizes, int n_in,
                              void* d_out, int out_size, void* d_ws, size_t ws_size,
                              hipStream_t stream) {
    const float* x       = (const float*)d_in[0];
    const int*   kmer    = (const int*)  d_in[1];
    const int*   indices = (const int*)  d_in[2];
    const float* emb     = (const float*)d_in[3];
    const float* W1      = (const float*)d_in[4];
    const float* b1      = (const float*)d_in[5];
    const float* W2      = (const float*)d_in[6];
    const float* b2      = (const float*)d_in[7];
    const float* W3      = (const float*)d_in[8];
    const float* b3      = (const float*)d_in[9];
    const float* W4      = (const float*)d_in[10];
    const float* b4      = (const float*)d_in[11];

    float* out = (float*)d_out;
    const int G = out_size;

    const int grid = (G + 31) / 32;              // 32 sites / block
    k_all<<<grid, 256, 0, stream>>>(x, kmer, indices, emb,
                                    W1, b1, W2, b2, W3, b3, W4, b4,
                                    out, G);
}

// Round 14
// 35.691 us; speedup vs baseline: 4.5465x; 1.0398x over previous
//
#include <hip/hip_runtime.h>
#include <hip/hip_bf16.h>
#include <hip/hip_fp16.h>
#include <math.h>

#define HDIM 150

typedef __bf16   bf16x8 __attribute__((ext_vector_type(8)));
typedef __fp16   f16x8  __attribute__((ext_vector_type(8)));   // matches builtin 'h'
typedef __fp16   f16x2  __attribute__((ext_vector_type(2)));
typedef float    f32x4  __attribute__((ext_vector_type(4)));

__device__ __forceinline__ unsigned int pk16(float a, float b) {
    f16x2 p = __builtin_amdgcn_cvt_pkrtz(a, b);
    unsigned int w; __builtin_memcpy(&w, &p, 4);
    return w;
}

__device__ __forceinline__ f16x2 swap_halves(f16x2 v) {
    unsigned int u; __builtin_memcpy(&u, &v, 4);
    u = __builtin_amdgcn_alignbit(u, u, 16);
    f16x2 r; __builtin_memcpy(&r, &u, 4);
    return r;
}

// ---------------------------------------------------------------------------
// fully unrolled Batcher odd-even mergesort, n = 16 (element type generic;
// f16x2 sorts lows and highs INDEPENDENTLY via v_pk_min/max_f16)
// ---------------------------------------------------------------------------
template <typename T>
__device__ __forceinline__ void cswapT(T& a, T& b) {
    T lo = __builtin_elementwise_min(a, b);
    T hi = __builtin_elementwise_max(a, b);
    a = lo; b = hi;
}

template <typename T>
__device__ __forceinline__ void sort16t(T v[16]) {
#pragma unroll
    for (int pp = 1; pp < 16; pp <<= 1) {
#pragma unroll
        for (int k = pp; k >= 1; k >>= 1) {
#pragma unroll
            for (int j = k & (pp - 1); j + k < 16; j += 2 * k) {
#pragma unroll
                for (int i = 0; i < k; ++i) {
                    if ((i + j) / (2 * pp) == (i + j + k) / (2 * pp))
                        cswapT(v[i + j], v[i + j + k]);
                }
            }
        }
    }
}

// ---------------------------------------------------------------------------
// k_all R22: R21 + packed-f16 aggregation diet.
// R21 post-mortem: reg-frags bought 1.3us; remaining cost is instruction
// count, largest block = agg (~580 instr/thread). Diet:
//  * sH transposed to [site][p][mm], p-stride 40 f16 (80B): agg reads are
//    4 x ds_read_b128 (was 32 x ds_read_u16); bank-quads tile perfectly.
//    MLP h-write becomes 4 x u16 (2-way bank alias = free).
//  * PACKED sort: f16x2 Batcher sort16 (v_pk_min/max) sorts even-indexed
//    reads (lows) and odd-indexed (highs) simultaneously: 126 ops vs 252.
//    Lower-median-of-32 identity needs any partition into two sorted 16s.
//    Merge: m_i = pk_min(v[i], swap_halves(v[15-i])); med = max_i m_i.lo
//    (highs are lows reversed). min/max free from v[0]/v[15].
//  * sum/sumsq via v_dot2_f32_f16 (exact f16 mul + f32 acc): 32 fdot2
//    replace ~96 scalar cvt/add/fma.
//  * MLP->agg barrier removed (agg reads same-wave sites only); sAgg
//    overlays the blob region, made safe by a cheap barrier right after
//    the per-lane fragment pull (bar2b).
//
// LDS overlay (35840 B, 4 blocks/CU):
//   [0,20480)      phase A: W1|b1@2700|W2@2850 staging (f32, 16200B)
//                  phase B: sH  32 x (8 x 40) f16 = 640B/site
//                  phase D: W3 staging (bf16, 12000B)   [after bar4]
//   [20480,35840)  phase A: frag blob, 15 tiles x 1KB (read once at bar2b)
//                  phase C: sAgg (5632) @20480 | sB3 @26112 | sW4 @26752 |
//                           sPart @27392   (overlays dead blob tiles)
// Barriers: bar1 (W staged) -> bar2 (blob built) -> pull frags -> bar2b ->
// MLP -> [none] -> agg -> bar4 -> W3/b3/W4 write -> bar5 -> head -> bar6.
// ---------------------------------------------------------------------------
#define FB_OFF     20480
#define AGG_OFF    20480
#define B3_OFF     26112
#define W4_OFF     26752
#define PART_OFF   27392
#define SMEM_TOTAL 35840

__global__ __launch_bounds__(256, 4) void k_all(
    const float* __restrict__ x, const int* __restrict__ kmer,
    const int* __restrict__ indices, const float* __restrict__ emb,
    const float* __restrict__ W1, const float* __restrict__ b1,
    const float* __restrict__ W2, const float* __restrict__ b2,
    const float* __restrict__ W3, const float* __restrict__ b3,
    const float* __restrict__ W4, const float* __restrict__ b4,
    float* __restrict__ out, int Gtot)
{
    __shared__ __align__(16) char smem[SMEM_TOTAL];

    const int tid  = threadIdx.x;
    const int lane = tid & 63;
    const int wv   = tid >> 6;
    const int m    = lane & 15;
    const int q    = lane >> 4;

    const int gblk  = blockIdx.x * 32;           // first site of this block
    const int rbase = gblk * 32;                 // first flat read-slot

    // ---- read indices + emb chain (4 groups of 64 reads per wave) ----
    int          rg[4];
    unsigned int egp[4];                         // packed f16 (ex,ey)
    {
        const int lim = Gtot * 32 - 1;
#pragma unroll
        for (int g = 0; g < 4; ++g) {
            int fl = rbase + wv * 256 + g * 64 + lane;
            rg[g] = indices[fl > lim ? lim : fl];
        }
        int kk[4];
#pragma unroll
        for (int g = 0; g < 4; ++g) kk[g] = kmer[rg[g]];
        const float2* emb2 = (const float2*)emb;
#pragma unroll
        for (int g = 0; g < 4; ++g) {
            float2 e = emb2[kk[g]];
            egp[g] = pk16(e.x, e.y);
        }
    }

    // ---- phase A: stage W1|b1|W2, build f16 fragment blob in LDS ----
    float* sWgt = (float*)smem;                  // [0,16200) bytes as f32
    for (int e = tid; e < 2700; e += 256) sWgt[e] = W1[e];
    for (int e = tid; e < 150;  e += 256) sWgt[2700 + e] = b1[e];
    for (int e = tid; e < 1200; e += 256) sWgt[2850 + e] = W2[e];
    __syncthreads();                             // bar1

    uint4* fb4w = (uint4*)(smem + FB_OFF);
    {
        const int c  = tid >> 6;                 // tile chunk 0..3
        const int tn = (c < 3) ? 4 : 3;          // tiles 0..14
        for (int tt = 0; tt < tn; ++tt) {
            const int tile = c * 4 + tt;
            unsigned int w[4];
#pragma unroll
            for (int dw = 0; dw < 4; ++dw) {
                const int d = tile * 4 + dw;
                float v0 = 0.f, v1 = 0.f;
                if (d < 40) {
                    int n = d >> 2, j0 = (d & 3) * 2;
                    // permuted hidden rows for the register relay:
                    //   tile 2kt   row(4q+r) = hidden 32kt+8q+r
                    //   tile 2kt+1 row(4q+r) = hidden 32kt+8q+4+r
                    int hid = 32 * (n >> 1) + 8 * (m >> 2) + 4 * (n & 1) + (m & 3);
                    if (hid < HDIM) {
                        int k0 = q * 8 + j0, k1 = k0 + 1;
                        v0 = (k0 < 18) ? sWgt[k0 * HDIM + hid] : (k0 == 18 ? sWgt[2700 + hid] : 0.f);
                        v1 = (k1 < 18) ? sWgt[k1 * HDIM + hid] : (k1 == 18 ? sWgt[2700 + hid] : 0.f);
                    }
                } else {
                    int kt = (d - 40) >> 2, j0 = ((d - 40) & 3) * 2;
                    int k0 = kt * 32 + q * 8 + j0, k1 = k0 + 1;
                    if (m < 8) {
                        v0 = (k0 < HDIM) ? sWgt[2850 + k0 * 8 + m]
                                         : (k0 == HDIM ? b2[m] : 0.f);   // b2 row
                        v1 = (k1 < HDIM) ? sWgt[2850 + k1 * 8 + m]
                                         : (k1 == HDIM ? b2[m] : 0.f);
                    }
                }
                w[dw] = pk16(v0, v1);
            }
            fb4w[tile * 64 + lane] = make_uint4(w[0], w[1], w[2], w[3]);
        }
    }
    __syncthreads();                             // bar2 (sWgt dead)

    // ---- ALL 15 fragment tiles pulled into registers (read LDS once) ----
    uint4 B16[15];
    const uint4* fb4 = (const uint4*)fb4w;
#pragma unroll
    for (int i = 0; i < 15; ++i) B16[i] = fb4[i * 64 + lane];
    const f16x8* frv = (const f16x8*)B16;        // frv[0..9]=L1, frv[10..14]=L2
    __syncthreads();                             // bar2b: blob region reusable

    const char* xg = (const char*)x;

    // ---- 2-tile-deep register pipeline for the x gather ----
    f32x4 xa[2][2];
    auto issueTile = [&](int t) {
        int rr = __shfl(rg[t >> 2], ((t & 3) << 4) + m);
        if (q < 2) {
            const f32x4* src = (const f32x4*)(xg + (size_t)rr * 64 + (size_t)q * 32);
            xa[t & 1][0] = src[0];
            xa[t & 1][1] = src[1];
        }
    };
    issueTile(0);
    issueTile(1);

    __fp16* sH = (__fp16*)smem;                  // overlays dead sWgt
    const f32x4 zero = {0.f, 0.f, 0.f, 0.f};
    const f16x2 z2 = {};

#pragma unroll
    for (int t = 0; t < 16; ++t) {
        unsigned int ew = __shfl((int)egp[t >> 2], ((t & 3) << 4) + m);

        // input B-fragment: B[k = q*8+j][n = read m]
        f16x8 bin;
#pragma unroll
        for (int j = 0; j < 8; ++j) bin[j] = (__fp16)0.f;
        if (q < 2) {
            f32x4 u0 = xa[t & 1][0];
            f32x4 u1 = xa[t & 1][1];
            f16x2 p0 = __builtin_amdgcn_cvt_pkrtz(u0[0], u0[1]);
            f16x2 p1 = __builtin_amdgcn_cvt_pkrtz(u0[2], u0[3]);
            f16x2 p2 = __builtin_amdgcn_cvt_pkrtz(u1[0], u1[1]);
            f16x2 p3 = __builtin_amdgcn_cvt_pkrtz(u1[2], u1[3]);
            bin[0] = p0[0]; bin[1] = p0[1]; bin[2] = p1[0]; bin[3] = p1[1];
            bin[4] = p2[0]; bin[5] = p2[1]; bin[6] = p3[0]; bin[7] = p3[1];
        } else if (q == 2) {
            f16x2 ep; __builtin_memcpy(&ep, &ew, 4);
            bin[0] = ep[0]; bin[1] = ep[1];
            bin[2] = (__fp16)1.0f;   // bias-1 input at k==18
        }

        // refill this ring slot with tile t+2 (loads overlap the MFMAs)
        if (t < 14) issueTile(t + 2);

        // layer1 (reg frags) -> packed relu -> layer2 (reg frags)
        f32x4 c2a = zero, c2b = zero;
#pragma unroll
        for (int kt = 0; kt < 5; ++kt) {
            f32x4 ca = __builtin_amdgcn_mfma_f32_16x16x32_f16(frv[2 * kt],     bin, zero, 0, 0, 0);
            f32x4 cb = __builtin_amdgcn_mfma_f32_16x16x32_f16(frv[2 * kt + 1], bin, zero, 0, 0, 0);
            f16x2 h01 = __builtin_elementwise_max(__builtin_amdgcn_cvt_pkrtz(ca[0], ca[1]), z2);
            f16x2 h23 = __builtin_elementwise_max(__builtin_amdgcn_cvt_pkrtz(ca[2], ca[3]), z2);
            f16x2 h45 = __builtin_elementwise_max(__builtin_amdgcn_cvt_pkrtz(cb[0], cb[1]), z2);
            f16x2 h67 = __builtin_elementwise_max(__builtin_amdgcn_cvt_pkrtz(cb[2], cb[3]), z2);
            f16x8 bh;
            bh[0] = h01[0]; bh[1] = h01[1]; bh[2] = h23[0]; bh[3] = h23[1];
            bh[4] = h45[0]; bh[5] = h45[1]; bh[6] = h67[0]; bh[7] = h67[1];
            if (kt == 4 && q == 2) bh[6] = (__fp16)1.0f;   // bias row k==150
            if (kt & 1) c2b = __builtin_amdgcn_mfma_f32_16x16x32_f16(frv[10 + kt], bh, c2b, 0, 0, 0);
            else        c2a = __builtin_amdgcn_mfma_f32_16x16x32_f16(frv[10 + kt], bh, c2a, 0, 0, 0);
        }

        // h -> LDS transposed layout [site][p (stride 40)][mm]
        if (q < 2) {
            int br   = wv * 256 + t * 16 + m;    // block read idx
            int site = br >> 5, mm = br & 31;
            float s0 = c2a[0] + c2b[0], s1 = c2a[1] + c2b[1];
            float s2 = c2a[2] + c2b[2], s3 = c2a[3] + c2b[3];
            f16x2 o01 = __builtin_elementwise_max(__builtin_amdgcn_cvt_pkrtz(s0, s1), z2);
            f16x2 o23 = __builtin_elementwise_max(__builtin_amdgcn_cvt_pkrtz(s2, s3), z2);
            __fp16* hb = sH + site * 320 + mm;
            hb[(q * 4 + 0) * 40] = o01[0];
            hb[(q * 4 + 1) * 40] = o01[1];
            hb[(q * 4 + 2) * 40] = o23[0];
            hb[(q * 4 + 3) * 40] = o23[1];
        }
    }
    // NO barrier: agg reads only this wave's own sites (same-wave RAW via
    // lgkmcnt); sAgg region was freed at bar2b.

    float* sAgg = (float*)(smem + AGG_OFF);
    float* sPart= (float*)(smem + PART_OFF);

    // ---- T14 async-stage: issue W3/b3/W4 loads now; agg hides the latency --
    float w3r[24];
#pragma unroll
    for (int i = 0; i < 24; ++i) {
        int e = tid + i * 256;
        w3r[i] = (e < 6000) ? W3[e] : 0.f;
    }
    float b3r = 0.f, w4r = 0.f;
    if (tid < 160) {
        b3r = (tid < HDIM) ? b3[tid] : 0.f;
        w4r = (tid < HDIM) ? W4[tid] : 0.f;
    }

    // ---- aggregation: packed f16 stats + packed sort + halver merge ----
    const int sg = tid >> 3, p = tid & 7;
    {
        const __fp16* hp = sH + sg * 320 + p * 40;
        uint4 rr4[4];
#pragma unroll
        for (int c = 0; c < 4; ++c) rr4[c] = *(const uint4*)(hp + c * 8);
        f16x2 v[16];                             // v[k] = (read 2k, read 2k+1)
        __builtin_memcpy(v, rr4, 64);

        // sum / sumsq via v_dot2_f32_f16 (exact f16 mul, f32 accumulate)
        float sum = 0.f, sumsq = 0.f;
        const f16x2 ones = {(__fp16)1.0f, (__fp16)1.0f};
#pragma unroll
        for (int k = 0; k < 16; ++k) {
            sum   = __builtin_amdgcn_fdot2(v[k], ones, sum, false);
            sumsq = __builtin_amdgcn_fdot2(v[k], v[k], sumsq, false);
        }

        // packed sort: lows = sorted even reads, highs = sorted odd reads
        sort16t(v);

        float mn = fminf((float)v[0][0],  (float)v[0][1]);
        float mx = fmaxf((float)v[15][0], (float)v[15][1]);

        // lower median of 32 = max_i min(a[i], b[15-i]); highs mirror lows
        f16x2 medv = __builtin_elementwise_min(v[0], swap_halves(v[15]));
#pragma unroll
        for (int i = 1; i < 16; ++i)
            medv = __builtin_elementwise_max(
                medv, __builtin_elementwise_min(v[i], swap_halves(v[15 - i])));
        float med = (float)medv[0];

        float mean = sum * (1.f / 32.f);
        float var  = fmaxf((sumsq - 32.f * mean * mean) * (1.f / 31.f), 0.f);
        sAgg[sg * 44 + 0 * 8 + p] = mean;
        sAgg[sg * 44 + 1 * 8 + p] = var;
        sAgg[sg * 44 + 2 * 8 + p] = mn;
        sAgg[sg * 44 + 3 * 8 + p] = med;
        sAgg[sg * 44 + 4 * 8 + p] = mx;
    }
    __syncthreads();   // bar4: all agg done; sH dead -> stage W3 at base

    // ---- phase D: write staged W3 as bf16 (+b3/W4 f32) ----
    __bf16* sW3b = (__bf16*)smem;                // 6000 bf16 = 12000 B
    float*  sB3  = (float*)(smem + B3_OFF);
    float*  sW4  = (float*)(smem + W4_OFF);
#pragma unroll
    for (int i = 0; i < 24; ++i) {
        int e = tid + i * 256;
        if (e < 6000) sW3b[e] = (__bf16)w3r[i];
    }
    if (tid < 160) { sB3[tid] = b3r; sW4[tid] = w4r; }
    __syncthreads();   // bar5

    // head A-fragment: tile (jt,kc): A[row=jt*16+m][k=kc*32+q*8+j] = W3[k][row]
    const int jthalf = wv >> 1, sh = wv & 1;
    uint4 HF[10];
#pragma unroll
    for (int i = 0; i < 10; ++i) {
        int jt = jthalf * 5 + (i >> 1), kc = i & 1;
        int row = jt * 16 + m;
        unsigned int w[4];
#pragma unroll
        for (int dw = 0; dw < 4; ++dw) {
            int k0 = kc * 32 + q * 8 + dw * 2, k1 = k0 + 1;
            unsigned short u0 = 0, u1 = 0;
            if (row < HDIM) {
                if (k0 < 40) __builtin_memcpy(&u0, &sW3b[k0 * HDIM + row], 2);
                if (k1 < 40) __builtin_memcpy(&u1, &sW3b[k1 * HDIM + row], 2);
            }
            w[dw] = (unsigned int)u0 | ((unsigned int)u1 << 16);
        }
        HF[i] = make_uint4(w[0], w[1], w[2], w[3]);
    }
    const bf16x8* hf = (const bf16x8*)HF;

    // ---- head MLP via MFMA: Z[j][site] = W3^T @ AGG, wave = (jthalf, sh) ----
    // B-frag: lane(m,q) holds AGG[k = kc*32+q*8+j][site sh*16+m], split hi/lo
    const int site = sh * 16 + m;
    const float* ar = sAgg + site * 44;
    bf16x8 bh0, bl0, bh1, bl1;
    {
        float4 a0 = *(const float4*)(ar + q * 8);
        float4 a1 = *(const float4*)(ar + q * 8 + 4);
        float va[8] = {a0.x, a0.y, a0.z, a0.w, a1.x, a1.y, a1.z, a1.w};
#pragma unroll
        for (int j = 0; j < 8; ++j) {
            __bf16 hi = (__bf16)va[j];
            bh0[j] = hi;
            bl0[j] = (__bf16)(va[j] - (float)hi);
        }
    }
    if (q == 0) {       // kc=1 covers k = 32..39 (stat 4); other q are zero
        float4 a0 = *(const float4*)(ar + 32);
        float4 a1 = *(const float4*)(ar + 36);
        float va[8] = {a0.x, a0.y, a0.z, a0.w, a1.x, a1.y, a1.z, a1.w};
#pragma unroll
        for (int j = 0; j < 8; ++j) {
            __bf16 hi = (__bf16)va[j];
            bh1[j] = hi;
            bl1[j] = (__bf16)(va[j] - (float)hi);
        }
    } else {
#pragma unroll
        for (int j = 0; j < 8; ++j) { bh1[j] = (__bf16)0.f; bl1[j] = (__bf16)0.f; }
    }

    const float4* b3v = (const float4*)sB3;
    const float4* w4v = (const float4*)sW4;
    float sacc = 0.f;
#pragma unroll
    for (int jj = 0; jj < 5; ++jj) {
        int jt = jthalf * 5 + jj;
        float4 bi = b3v[jt * 4 + q];             // rows jt*16+q*4 .. +3
        f32x4 acc = {bi.x, bi.y, bi.z, bi.w};
        acc = __builtin_amdgcn_mfma_f32_16x16x32_bf16(hf[jj * 2 + 0], bh0, acc, 0, 0, 0);
        acc = __builtin_amdgcn_mfma_f32_16x16x32_bf16(hf[jj * 2 + 0], bl0, acc, 0, 0, 0);
        acc = __builtin_amdgcn_mfma_f32_16x16x32_bf16(hf[jj * 2 + 1], bh1, acc, 0, 0, 0);
        acc = __builtin_amdgcn_mfma_f32_16x16x32_bf16(hf[jj * 2 + 1], bl1, acc, 0, 0, 0);
        float4 w4q = w4v[jt * 4 + q];
        sacc = fmaf(fmaxf(acc[0], 0.f), w4q.x, sacc);
        sacc = fmaf(fmaxf(acc[1], 0.f), w4q.y, sacc);
        sacc = fmaf(fmaxf(acc[2], 0.f), w4q.z, sacc);
        sacc = fmaf(fmaxf(acc[3], 0.f), w4q.w, sacc);
    }
    // reduce over the 4 q row-groups (j within tile), then across jthalf waves
    sacc += __shfl_xor(sacc, 16);
    sacc += __shfl_xor(sacc, 32);
    if (jthalf == 1 && lane < 16) sPart[sh * 16 + lane] = sacc;
    __syncthreads();   // bar6
    if (jthalf == 0 && lane < 16) {
        int s2 = sh * 16 + lane;
        float zf = sacc + sPart[s2] + b4[0];
        if (gblk + s2 < Gtot) out[gblk + s2] = 1.f / (1.f + expf(-zf));
    }
}

// ---------------------------------------------------------------------------
extern "C" void kernel_launch(void* const* d_in, const int* in_sizes, int n_in,
                              void* d_out, int out_size, void* d_ws, size_t ws_size,
                              hipStream_t stream) {
    const float* x       = (const float*)d_in[0];
    const int*   kmer    = (const int*)  d_in[1];
    const int*   indices = (const int*)  d_in[2];
    const float* emb     = (const float*)d_in[3];
    const float* W1      = (const float*)d_in[4];
    const float* b1      = (const float*)d_in[5];
    const float* W2      = (const float*)d_in[6];
    const float* b2      = (const float*)d_in[7];
    const float* W3      = (const float*)d_in[8];
    const float* b3      = (const float*)d_in[9];
    const float* W4      = (const float*)d_in[10];
    const float* b4      = (const float*)d_in[11];

    float* out = (float*)d_out;
    const int G = out_size;

    const int grid = (G + 31) / 32;              // 32 sites / block
    k_all<<<grid, 256, 0, stream>>>(x, kmer, indices, emb,
                                    W1, b1, W2, b2, W3, b3, W4, b4,
                                    out, G);
}

// Round 16
// 31.223 us; speedup vs baseline: 5.1970x; 1.1431x over previous
//
#include <hip/hip_runtime.h>
#include <hip/hip_bf16.h>
#include <hip/hip_fp16.h>
#include <math.h>

#define HDIM 150

typedef __fp16   f16x8  __attribute__((ext_vector_type(8)));   // matches builtin 'h'
typedef __fp16   f16x2  __attribute__((ext_vector_type(2)));
typedef float    f32x4  __attribute__((ext_vector_type(4)));

__device__ __forceinline__ unsigned int pk16(float a, float b) {
    f16x2 p = __builtin_amdgcn_cvt_pkrtz(a, b);
    unsigned int w; __builtin_memcpy(&w, &p, 4);
    return w;
}

__device__ __forceinline__ f16x2 swap_halves(f16x2 v) {
    unsigned int u; __builtin_memcpy(&u, &v, 4);
    u = __builtin_amdgcn_alignbit(u, u, 16);
    f16x2 r; __builtin_memcpy(&r, &u, 4);
    return r;
}

// ---------------------------------------------------------------------------
// fully unrolled Batcher odd-even mergesort, n = 16 (f16x2: lows and highs
// sorted INDEPENDENTLY via v_pk_min/max_f16)
// ---------------------------------------------------------------------------
template <typename T>
__device__ __forceinline__ void cswapT(T& a, T& b) {
    T lo = __builtin_elementwise_min(a, b);
    T hi = __builtin_elementwise_max(a, b);
    a = lo; b = hi;
}

template <typename T>
__device__ __forceinline__ void sort16t(T v[16]) {
#pragma unroll
    for (int pp = 1; pp < 16; pp <<= 1) {
#pragma unroll
        for (int k = pp; k >= 1; k >>= 1) {
#pragma unroll
            for (int j = k & (pp - 1); j + k < 16; j += 2 * k) {
#pragma unroll
                for (int i = 0; i < k; ++i) {
                    if ((i + j) / (2 * pp) == (i + j + k) / (2 * pp))
                        cswapT(v[i + j], v[i + j + k]);
                }
            }
        }
    }
}

// ---------------------------------------------------------------------------
// k_all R24: R23 with the head-frag staging bug fixed.
// R23 failed correctness: the transposed staging built only 10 HF tiles
// (jt 0..4, rows 0..79) while the head reads 20 (jt 0..9, rows 0..159 for
// HDIM=150); tiles 10..19 were stale sH garbage. Fix: each thread owns its
// fragment dword in ALL 20 tiles (j=0..19), loads its 40 W3 values (L2-hot,
// issued before agg -> latency hidden), PACKS IMMEDIATELY to 20 dwords
// (hw[20] = 20 VGPRs, not 40 floats -- stays under the 128-reg cliff), and
// ds_write_b32's them after bar4. hfT = 20 x 1KB = 20480 B = exactly the
// dead sH region. Reader unchanged.
// Kept diets: f16 MFMA everywhere (relay + head, hi/lo split on head B),
// direct-global blob build (no sWgt staging, no bar1), packed relu/sort,
// fdot2 stats, sH [site][p][mm] stride-40, no MLP->agg barrier.
//
// LDS overlay (35840 B, 4 blocks/CU):
//   [0,20480)      phase B: sH  32 x (8 x 40) f16 = 640B/site
//                  phase D: head frag tiles, 20 x 1KB  [after bar4]
//   [20480,35840)  phase A: MLP frag blob, 15 tiles x 1KB (pulled at barB)
//                  phase C: sAgg (5632) @20480 | sB3 @26112 | sW4 @26752 |
//                           sPart @27392   (overlays dead blob tiles)
// Barriers: barA (blob built) -> pull -> barB (blob dead) -> MLP ->
// [none] -> agg -> bar4 (sH dead) -> frag/b3/W4 writes -> bar5 -> head ->
// bar6 -> out.
// ---------------------------------------------------------------------------
#define FB_OFF     20480
#define AGG_OFF    20480
#define B3_OFF     26112
#define W4_OFF     26752
#define PART_OFF   27392
#define SMEM_TOTAL 35840

__global__ __launch_bounds__(256, 4) void k_all(
    const float* __restrict__ x, const int* __restrict__ kmer,
    const int* __restrict__ indices, const float* __restrict__ emb,
    const float* __restrict__ W1, const float* __restrict__ b1,
    const float* __restrict__ W2, const float* __restrict__ b2,
    const float* __restrict__ W3, const float* __restrict__ b3,
    const float* __restrict__ W4, const float* __restrict__ b4,
    float* __restrict__ out, int Gtot)
{
    __shared__ __align__(16) char smem[SMEM_TOTAL];

    const int tid  = threadIdx.x;
    const int lane = tid & 63;
    const int wv   = tid >> 6;
    const int m    = lane & 15;
    const int q    = lane >> 4;

    const int gblk  = blockIdx.x * 32;           // first site of this block
    const int rbase = gblk * 32;                 // first flat read-slot

    // ---- read indices + emb chain (4 groups of 64 reads per wave) ----
    int          rg[4];
    unsigned int egp[4];                         // packed f16 (ex,ey)
    {
        const int lim = Gtot * 32 - 1;
#pragma unroll
        for (int g = 0; g < 4; ++g) {
            int fl = rbase + wv * 256 + g * 64 + lane;
            rg[g] = indices[fl > lim ? lim : fl];
        }
        int kk[4];
#pragma unroll
        for (int g = 0; g < 4; ++g) kk[g] = kmer[rg[g]];
        const float2* emb2 = (const float2*)emb;
#pragma unroll
        for (int g = 0; g < 4; ++g) {
            float2 e = emb2[kk[g]];
            egp[g] = pk16(e.x, e.y);
        }
    }

    // ---- phase A: build f16 fragment blob in LDS, weights read straight
    //      from global (L2-resident; staging through LDS was pure overhead)
    uint4* fb4w = (uint4*)(smem + FB_OFF);
    {
        const int c  = tid >> 6;                 // tile chunk 0..3
        const int tn = (c < 3) ? 4 : 3;          // tiles 0..14
        for (int tt = 0; tt < tn; ++tt) {
            const int tile = c * 4 + tt;
            unsigned int w[4];
#pragma unroll
            for (int dw = 0; dw < 4; ++dw) {
                const int d = tile * 4 + dw;
                float v0 = 0.f, v1 = 0.f;
                if (d < 40) {
                    int n = d >> 2, j0 = (d & 3) * 2;
                    // permuted hidden rows for the register relay:
                    //   tile 2kt   row(4q+r) = hidden 32kt+8q+r
                    //   tile 2kt+1 row(4q+r) = hidden 32kt+8q+4+r
                    int hid = 32 * (n >> 1) + 8 * (m >> 2) + 4 * (n & 1) + (m & 3);
                    if (hid < HDIM) {
                        int k0 = q * 8 + j0, k1 = k0 + 1;
                        v0 = (k0 < 18) ? W1[k0 * HDIM + hid] : (k0 == 18 ? b1[hid] : 0.f);
                        v1 = (k1 < 18) ? W1[k1 * HDIM + hid] : (k1 == 18 ? b1[hid] : 0.f);
                    }
                } else {
                    int kt = (d - 40) >> 2, j0 = ((d - 40) & 3) * 2;
                    int k0 = kt * 32 + q * 8 + j0, k1 = k0 + 1;
                    if (m < 8) {
                        v0 = (k0 < HDIM) ? W2[k0 * 8 + m]
                                         : (k0 == HDIM ? b2[m] : 0.f);   // b2 row
                        v1 = (k1 < HDIM) ? W2[k1 * 8 + m]
                                         : (k1 == HDIM ? b2[m] : 0.f);
                    }
                }
                w[dw] = pk16(v0, v1);
            }
            fb4w[tile * 64 + lane] = make_uint4(w[0], w[1], w[2], w[3]);
        }
    }
    __syncthreads();                             // barA (blob built)

    // ---- ALL 15 fragment tiles pulled into registers (read LDS once) ----
    uint4 B16[15];
    const uint4* fb4 = (const uint4*)fb4w;
#pragma unroll
    for (int i = 0; i < 15; ++i) B16[i] = fb4[i * 64 + lane];
    const f16x8* frv = (const f16x8*)B16;        // frv[0..9]=L1, frv[10..14]=L2
    __syncthreads();                             // barB: blob region reusable

    const char* xg = (const char*)x;

    // ---- 2-tile-deep register pipeline for the x gather ----
    f32x4 xa[2][2];
    auto issueTile = [&](int t) {
        int rr = __shfl(rg[t >> 2], ((t & 3) << 4) + m);
        if (q < 2) {
            const f32x4* src = (const f32x4*)(xg + (size_t)rr * 64 + (size_t)q * 32);
            xa[t & 1][0] = src[0];
            xa[t & 1][1] = src[1];
        }
    };
    issueTile(0);
    issueTile(1);

    __fp16* sH = (__fp16*)smem;
    const f32x4 zero = {0.f, 0.f, 0.f, 0.f};
    const f16x2 z2 = {};

#pragma unroll
    for (int t = 0; t < 16; ++t) {
        unsigned int ew = __shfl((int)egp[t >> 2], ((t & 3) << 4) + m);

        // input B-fragment: B[k = q*8+j][n = read m]
        f16x8 bin;
#pragma unroll
        for (int j = 0; j < 8; ++j) bin[j] = (__fp16)0.f;
        if (q < 2) {
            f32x4 u0 = xa[t & 1][0];
            f32x4 u1 = xa[t & 1][1];
            f16x2 p0 = __builtin_amdgcn_cvt_pkrtz(u0[0], u0[1]);
            f16x2 p1 = __builtin_amdgcn_cvt_pkrtz(u0[2], u0[3]);
            f16x2 p2 = __builtin_amdgcn_cvt_pkrtz(u1[0], u1[1]);
            f16x2 p3 = __builtin_amdgcn_cvt_pkrtz(u1[2], u1[3]);
            bin[0] = p0[0]; bin[1] = p0[1]; bin[2] = p1[0]; bin[3] = p1[1];
            bin[4] = p2[0]; bin[5] = p2[1]; bin[6] = p3[0]; bin[7] = p3[1];
        } else if (q == 2) {
            f16x2 ep; __builtin_memcpy(&ep, &ew, 4);
            bin[0] = ep[0]; bin[1] = ep[1];
            bin[2] = (__fp16)1.0f;   // bias-1 input at k==18
        }

        // refill this ring slot with tile t+2 (loads overlap the MFMAs)
        if (t < 14) issueTile(t + 2);

        // layer1 (reg frags) -> packed relu -> layer2 (reg frags)
        f32x4 c2a = zero, c2b = zero;
#pragma unroll
        for (int kt = 0; kt < 5; ++kt) {
            f32x4 ca = __builtin_amdgcn_mfma_f32_16x16x32_f16(frv[2 * kt],     bin, zero, 0, 0, 0);
            f32x4 cb = __builtin_amdgcn_mfma_f32_16x16x32_f16(frv[2 * kt + 1], bin, zero, 0, 0, 0);
            f16x2 h01 = __builtin_elementwise_max(__builtin_amdgcn_cvt_pkrtz(ca[0], ca[1]), z2);
            f16x2 h23 = __builtin_elementwise_max(__builtin_amdgcn_cvt_pkrtz(ca[2], ca[3]), z2);
            f16x2 h45 = __builtin_elementwise_max(__builtin_amdgcn_cvt_pkrtz(cb[0], cb[1]), z2);
            f16x2 h67 = __builtin_elementwise_max(__builtin_amdgcn_cvt_pkrtz(cb[2], cb[3]), z2);
            f16x8 bh;
            bh[0] = h01[0]; bh[1] = h01[1]; bh[2] = h23[0]; bh[3] = h23[1];
            bh[4] = h45[0]; bh[5] = h45[1]; bh[6] = h67[0]; bh[7] = h67[1];
            if (kt == 4 && q == 2) bh[6] = (__fp16)1.0f;   // bias row k==150
            if (kt & 1) c2b = __builtin_amdgcn_mfma_f32_16x16x32_f16(frv[10 + kt], bh, c2b, 0, 0, 0);
            else        c2a = __builtin_amdgcn_mfma_f32_16x16x32_f16(frv[10 + kt], bh, c2a, 0, 0, 0);
        }

        // h -> LDS transposed layout [site][p (stride 40)][mm]
        if (q < 2) {
            int br   = wv * 256 + t * 16 + m;    // block read idx
            int site = br >> 5, mm = br & 31;
            float s0 = c2a[0] + c2b[0], s1 = c2a[1] + c2b[1];
            float s2 = c2a[2] + c2b[2], s3 = c2a[3] + c2b[3];
            f16x2 o01 = __builtin_elementwise_max(__builtin_amdgcn_cvt_pkrtz(s0, s1), z2);
            f16x2 o23 = __builtin_elementwise_max(__builtin_amdgcn_cvt_pkrtz(s2, s3), z2);
            __fp16* hb = sH + site * 320 + mm;
            hb[(q * 4 + 0) * 40] = o01[0];
            hb[(q * 4 + 1) * 40] = o01[1];
            hb[(q * 4 + 2) * 40] = o23[0];
            hb[(q * 4 + 3) * 40] = o23[1];
        }
    }
    // NO barrier: agg reads only this wave's own sites (same-wave RAW via
    // lgkmcnt); sAgg region was freed at barB.

    float* sAgg = (float*)(smem + AGG_OFF);
    float* sPart= (float*)(smem + PART_OFF);

    // ---- T14 async-stage, TRANSPOSED, ALL 20 TILES: thread t owns head-frag
    //      dword (tile j=0..19, lane t>>2, dw t&3); load its W3 pair now
    //      (L2-hot; agg hides latency), pack immediately (20 dwords, not 40
    //      floats), write to LDS after bar4.
    const int fl_ = tid >> 2, fdw = tid & 3;     // frag (lane, dword) owned
    const int fm = fl_ & 15, fq = fl_ >> 4;
    unsigned int hw[20];
#pragma unroll
    for (int j = 0; j < 20; ++j) {
        int jt = j >> 1, kc = j & 1;
        int row = jt * 16 + fm;
        int k0  = kc * 32 + fq * 8 + fdw * 2;
        float v0 = (k0     < 40 && row < HDIM) ? W3[k0 * HDIM + row]       : 0.f;
        float v1 = (k0 + 1 < 40 && row < HDIM) ? W3[(k0 + 1) * HDIM + row] : 0.f;
        hw[j] = pk16(v0, v1);
    }
    float b3r = 0.f, w4r = 0.f;
    if (tid < 160) {
        b3r = (tid < HDIM) ? b3[tid] : 0.f;
        w4r = (tid < HDIM) ? W4[tid] : 0.f;
    }

    // ---- aggregation: packed f16 stats + packed sort + halver merge ----
    const int sg = tid >> 3, p = tid & 7;
    {
        const __fp16* hp = sH + sg * 320 + p * 40;
        uint4 rr4[4];
#pragma unroll
        for (int c = 0; c < 4; ++c) rr4[c] = *(const uint4*)(hp + c * 8);
        f16x2 v[16];                             // v[k] = (read 2k, read 2k+1)
        __builtin_memcpy(v, rr4, 64);

        // sum / sumsq via v_dot2_f32_f16 (exact f16 mul, f32 accumulate)
        float sum = 0.f, sumsq = 0.f;
        const f16x2 ones = {(__fp16)1.0f, (__fp16)1.0f};
#pragma unroll
        for (int k = 0; k < 16; ++k) {
            sum   = __builtin_amdgcn_fdot2(v[k], ones, sum, false);
            sumsq = __builtin_amdgcn_fdot2(v[k], v[k], sumsq, false);
        }

        // packed sort: lows = sorted even reads, highs = sorted odd reads
        sort16t(v);

        float mn = fminf((float)v[0][0],  (float)v[0][1]);
        float mx = fmaxf((float)v[15][0], (float)v[15][1]);

        // lower median of 32 = max_i min(a[i], b[15-i]); highs mirror lows
        f16x2 medv = __builtin_elementwise_min(v[0], swap_halves(v[15]));
#pragma unroll
        for (int i = 1; i < 16; ++i)
            medv = __builtin_elementwise_max(
                medv, __builtin_elementwise_min(v[i], swap_halves(v[15 - i])));
        float med = (float)medv[0];

        float mean = sum * (1.f / 32.f);
        float var  = fmaxf((sumsq - 32.f * mean * mean) * (1.f / 31.f), 0.f);
        sAgg[sg * 44 + 0 * 8 + p] = mean;
        sAgg[sg * 44 + 1 * 8 + p] = var;
        sAgg[sg * 44 + 2 * 8 + p] = mn;
        sAgg[sg * 44 + 3 * 8 + p] = med;
        sAgg[sg * 44 + 4 * 8 + p] = mx;
    }
    __syncthreads();   // bar4: all agg done; sH dead -> head frag tiles there

    // ---- phase D: write head fragment tiles (f16) + b3/W4 ----
    unsigned int* hfT = (unsigned int*)smem;     // 20 tiles x 256 dwords
#pragma unroll
    for (int j = 0; j < 20; ++j)
        hfT[j * 256 + tid] = hw[j];
    float* sB3 = (float*)(smem + B3_OFF);
    float* sW4 = (float*)(smem + W4_OFF);
    if (tid < 160) { sB3[tid] = b3r; sW4[tid] = w4r; }
    __syncthreads();   // bar5

    // ---- lanes pull their 10 head-fragment uint4s ----
    const int jthalf = wv >> 1, sh = wv & 1;
    uint4 HF[10];
    {
        const uint4* hfv = (const uint4*)hfT;
#pragma unroll
        for (int i = 0; i < 10; ++i) {
            int jt = jthalf * 5 + (i >> 1), kc = i & 1;
            HF[i] = hfv[(jt * 2 + kc) * 64 + lane];
        }
    }
    const f16x8* hf = (const f16x8*)HF;

    // ---- head MLP via f16 MFMA: Z[j][site] = W3^T @ AGG, wave=(jthalf,sh) --
    // B-frag: lane(m,q) holds AGG[k = kc*32+q*8+j][site sh*16+m], split hi/lo
    const int site = sh * 16 + m;
    const float* ar = sAgg + site * 44;
    f16x8 bh0, bl0, bh1, bl1;
    {
        float4 a0 = *(const float4*)(ar + q * 8);
        float4 a1 = *(const float4*)(ar + q * 8 + 4);
        float va[8] = {a0.x, a0.y, a0.z, a0.w, a1.x, a1.y, a1.z, a1.w};
#pragma unroll
        for (int j = 0; j < 8; ++j) {
            __fp16 hi = (__fp16)va[j];
            bh0[j] = hi;
            bl0[j] = (__fp16)(va[j] - (float)hi);
        }
    }
    if (q == 0) {       // kc=1 covers k = 32..39 (stat 4); other q are zero
        float4 a0 = *(const float4*)(ar + 32);
        float4 a1 = *(const float4*)(ar + 36);
        float va[8] = {a0.x, a0.y, a0.z, a0.w, a1.x, a1.y, a1.z, a1.w};
#pragma unroll
        for (int j = 0; j < 8; ++j) {
            __fp16 hi = (__fp16)va[j];
            bh1[j] = hi;
            bl1[j] = (__fp16)(va[j] - (float)hi);
        }
    } else {
#pragma unroll
        for (int j = 0; j < 8; ++j) { bh1[j] = (__fp16)0.f; bl1[j] = (__fp16)0.f; }
    }

    const float4* b3v = (const float4*)sB3;
    const float4* w4v = (const float4*)sW4;
    float sacc = 0.f;
#pragma unroll
    for (int jj = 0; jj < 5; ++jj) {
        int jt = jthalf * 5 + jj;
        float4 bi = b3v[jt * 4 + q];             // rows jt*16+q*4 .. +3
        f32x4 acc = {bi.x, bi.y, bi.z, bi.w};
        acc = __builtin_amdgcn_mfma_f32_16x16x32_f16(hf[jj * 2 + 0], bh0, acc, 0, 0, 0);
        acc = __builtin_amdgcn_mfma_f32_16x16x32_f16(hf[jj * 2 + 0], bl0, acc, 0, 0, 0);
        acc = __builtin_amdgcn_mfma_f32_16x16x32_f16(hf[jj * 2 + 1], bh1, acc, 0, 0, 0);
        acc = __builtin_amdgcn_mfma_f32_16x16x32_f16(hf[jj * 2 + 1], bl1, acc, 0, 0, 0);
        float4 w4q = w4v[jt * 4 + q];
        sacc = fmaf(fmaxf(acc[0], 0.f), w4q.x, sacc);
        sacc = fmaf(fmaxf(acc[1], 0.f), w4q.y, sacc);
        sacc = fmaf(fmaxf(acc[2], 0.f), w4q.z, sacc);
        sacc = fmaf(fmaxf(acc[3], 0.f), w4q.w, sacc);
    }
    // reduce over the 4 q row-groups (j within tile), then across jthalf waves
    sacc += __shfl_xor(sacc, 16);
    sacc += __shfl_xor(sacc, 32);
    if (jthalf == 1 && lane < 16) sPart[sh * 16 + lane] = sacc;
    __syncthreads();   // bar6
    if (jthalf == 0 && lane < 16) {
        int s2 = sh * 16 + lane;
        float zf = sacc + sPart[s2] + b4[0];
        if (gblk + s2 < Gtot) out[gblk + s2] = 1.f / (1.f + expf(-zf));
    }
}

// ---------------------------------------------------------------------------
extern "C" void kernel_launch(void* const* d_in, const int* in_sizes, int n_in,
                              void* d_out, int out_size, void* d_ws, size_t ws_size,
                              hipStream_t stream) {
    const float* x       = (const float*)d_in[0];
    const int*   kmer    = (const int*)  d_in[1];
    const int*   indices = (const int*)  d_in[2];
    const float* emb     = (const float*)d_in[3];
    const float* W1      = (const float*)d_in[4];
    const float* b1      = (const float*)d_in[5];
    const float* W2      = (const float*)d_in[6];
    const float* b2      = (const float*)d_in[7];
    const float* W3      = (const float*)d_in[8];
    const float* b3      = (const float*)d_in[9];
    const float* W4      = (const float*)d_in[10];
    const float* b4      = (const float*)d_in[11];

    float* out = (float*)d_out;
    const int G = out_size;

    const int grid = (G + 31) / 32;              // 32 sites / block
    k_all<<<grid, 256, 0, stream>>>(x, kmer, indices, emb,
                                    W1, b1, W2, b2, W3, b3, W4, b4,
                                    out, G);
}